// Round 4
// baseline (308.516 us; speedup 1.0000x reference)
//
#include <hip/hip_runtime.h>

// Problem constants: B=2, S=4096, H=8, DH=64, D=512, M = B*S = 8192.
#define LOG2E 1.44269504088896340736f

typedef unsigned short u16;
typedef __bf16 bf16x4_t __attribute__((ext_vector_type(4)));
typedef __bf16 bf16x8_t __attribute__((ext_vector_type(8)));
typedef float f32x4_t __attribute__((ext_vector_type(4)));

__device__ __forceinline__ f32x4_t mfma16(bf16x8_t a, bf16x8_t b, f32x4_t c) {
  return __builtin_amdgcn_mfma_f32_16x16x32_bf16(a, b, c, 0, 0, 0);
}

// async 16B global -> LDS (dest = wave-uniform base + lane*16)
__device__ __forceinline__ void gl_lds16(const u16* g, u16* l) {
  __builtin_amdgcn_global_load_lds(
      (const __attribute__((address_space(1))) unsigned int*)g,
      (__attribute__((address_space(3))) unsigned int*)l, 16, 0, 0);
}

// ---------------- one-shot cast: fp32 -> bf16 (Wq pre-scaled by 0.125*log2e) --------------
__global__ __launch_bounds__(256) void cast_kernel(
    const float* __restrict__ x, const float* __restrict__ Wq, const float* __restrict__ Wk,
    const float* __restrict__ Wv, const float* __restrict__ Wo,
    u16* __restrict__ Xb, u16* __restrict__ Wqb, u16* __restrict__ Wkb,
    u16* __restrict__ Wvb, u16* __restrict__ Wob) {
  const int bid = blockIdx.x;
  const float* src;
  u16* dst;
  float scale = 1.f;
  int rel;
  if (bid < 2048)      { src = x;  dst = Xb;  rel = bid; }
  else if (bid < 2176) { src = Wq; dst = Wqb; rel = bid - 2048; scale = 0.125f * LOG2E; }
  else if (bid < 2304) { src = Wk; dst = Wkb; rel = bid - 2176; }
  else if (bid < 2432) { src = Wv; dst = Wvb; rel = bid - 2304; }
  else                 { src = Wo; dst = Wob; rel = bid - 2432; }
  const int i = rel * 2048 + threadIdx.x * 8;
  f32x4_t a = *(const f32x4_t*)(src + i) * scale;
  f32x4_t b = *(const f32x4_t*)(src + i + 4) * scale;
  union { uint4 u; struct { bf16x4_t lo, hi; } s; } c;
  c.s.lo = __builtin_convertvector(a, bf16x4_t);
  c.s.hi = __builtin_convertvector(b, bf16x4_t);
  *(uint4*)(dst + i) = c.u;
}

// ---------------- bf16 GEMM core (unchanged from round 3) --------------------------------
template <int MODE>
__device__ __forceinline__ void gemm_core_bf16(const u16* __restrict__ A, const u16* __restrict__ Bt,
                                               void* __restrict__ Cout, const float* __restrict__ bo,
                                               int Mbase, int Nbase) {
  __shared__ __align__(16) u16 smem[128 * 128];
  u16 (*As)[64] = (u16(*)[64])smem;
  u16 (*Bs)[64] = (u16(*)[64])(smem + 128 * 64);
  const int t = threadIdx.x;
  const int wave = t >> 6, lane = t & 63;
  const int r = lane & 15, qd = lane >> 4;
  const int wm = wave & 1, wn = wave >> 1;
  const int rr = lane >> 3;
  const int s8 = ((lane & 7) ^ (rr & 7)) * 8;

  f32x4_t acc[4][4];
#pragma unroll
  for (int i = 0; i < 4; i++)
#pragma unroll
    for (int j = 0; j < 4; j++) { f32x4_t z = {0.f, 0.f, 0.f, 0.f}; acc[i][j] = z; }

  const u16* pa = A  + (Mbase + wave * 32 + rr) * 512 + s8;
  const u16* pb = Bt + (Nbase + wave * 32 + rr) * 512 + s8;
  u16* la = &As[wave * 32][0];
  u16* lb = &Bs[wave * 32][0];

  for (int k0 = 0; k0 < 512; k0 += 64) {
#pragma unroll
    for (int j = 0; j < 4; j++) gl_lds16(pa + k0 + j * 8 * 512, la + j * 8 * 64);
#pragma unroll
    for (int j = 0; j < 4; j++) gl_lds16(pb + k0 + j * 8 * 512, lb + j * 8 * 64);
    __syncthreads();
#pragma unroll
    for (int h = 0; h < 2; h++) {
      bf16x8_t af[4], bfr[4];
#pragma unroll
      for (int i = 0; i < 4; i++)
        af[i]  = *(const bf16x8_t*)&As[wm * 64 + i * 16 + r][((h * 4 + qd) ^ (r & 7)) * 8];
#pragma unroll
      for (int j = 0; j < 4; j++)
        bfr[j] = *(const bf16x8_t*)&Bs[wn * 64 + j * 16 + r][((h * 4 + qd) ^ (r & 7)) * 8];
#pragma unroll
      for (int i = 0; i < 4; i++)
#pragma unroll
        for (int j = 0; j < 4; j++) acc[i][j] = mfma16(af[i], bfr[j], acc[i][j]);
    }
    __syncthreads();
  }

  if (MODE != 2) {
#pragma unroll
    for (int i = 0; i < 4; i++)
#pragma unroll
      for (int j = 0; j < 4; j++)
#pragma unroll
        for (int reg = 0; reg < 4; reg++) {
          int row = wm * 64 + i * 16 + qd * 4 + reg;
          int col = wn * 64 + j * 16 + r;
          __bf16 bv = (__bf16)acc[i][j][reg];
          smem[row * 128 + (col ^ (((row >> 2) & 7) << 3))] = *(u16*)&bv;
        }
    __syncthreads();
#pragma unroll
    for (int p = 0; p < 8; p++) {
      int row = p * 16 + (t >> 4);
      int col = (t & 15) * 8;
      uint4 v = *(const uint4*)&smem[row * 128 + (col ^ (((row >> 2) & 7) << 3))];
      if (MODE == 0) {
        *(uint4*)&((u16*)Cout)[(Mbase + row) * 512 + Nbase + col] = v;
      } else {
        int bb = Nbase >> 12;
        int ss = (Nbase & 4095) + col;
        *(uint4*)&((u16*)Cout)[((long)(bb * 512 + Mbase + row)) * 4096 + ss] = v;
      }
    }
  } else {
    float* stf = (float*)smem;
    float bv[4];
#pragma unroll
    for (int j = 0; j < 4; j++) bv[j] = bo[Nbase + wn * 64 + j * 16 + r];
#pragma unroll
    for (int hh = 0; hh < 2; hh++) {
      __syncthreads();
      if (wm == hh) {
#pragma unroll
        for (int i = 0; i < 4; i++)
#pragma unroll
          for (int j = 0; j < 4; j++)
#pragma unroll
            for (int reg = 0; reg < 4; reg++) {
              int row = i * 16 + qd * 4 + reg;
              int col = wn * 64 + j * 16 + r;
              stf[row * 128 + (col ^ (((row >> 2) & 7) << 2))] = acc[i][j][reg] + bv[j];
            }
      }
      __syncthreads();
#pragma unroll
      for (int p = 0; p < 4; p++) {
        int row = p * 16 + (t >> 4);
        int col = (t & 15) * 8;
        f32x4_t v0 = *(const f32x4_t*)&stf[row * 128 + ((col) ^ (((row >> 2) & 7) << 2))];
        f32x4_t v1 = *(const f32x4_t*)&stf[row * 128 + ((col + 4) ^ (((row >> 2) & 7) << 2))];
        *(f32x4_t*)&((float*)Cout)[(Mbase + hh * 64 + row) * 512 + Nbase + col] = v0;
        *(f32x4_t*)&((float*)Cout)[(Mbase + hh * 64 + row) * 512 + Nbase + col + 4] = v1;
      }
    }
  }
}

__global__ __launch_bounds__(256) void gemm_qkv_kernel(
    const u16* __restrict__ Xb,
    const u16* __restrict__ Wqb, const u16* __restrict__ Wkb, const u16* __restrict__ Wvb,
    u16* __restrict__ Q, u16* __restrict__ K, u16* __restrict__ Vt) {
  if (blockIdx.z == 0)
    gemm_core_bf16<0>(Xb, Wqb, Q, nullptr, blockIdx.x * 128, blockIdx.y * 128);
  else if (blockIdx.z == 1)
    gemm_core_bf16<0>(Xb, Wkb, K, nullptr, blockIdx.x * 128, blockIdx.y * 128);
  else  // V^T = Wv @ X^T
    gemm_core_bf16<1>(Wvb, Xb, Vt, nullptr, blockIdx.y * 128, blockIdx.x * 128);
}

__global__ __launch_bounds__(256) void gemm_out_kernel(
    const u16* __restrict__ Aat, const u16* __restrict__ Wob,
    float* __restrict__ Out, const float* __restrict__ bo) {
  gemm_core_bf16<2>(Aat, Wob, Out, bo, blockIdx.x * 128, blockIdx.y * 128);
}

// ---------------- flash attention v9: iteration-level software pipeline ------------------
// QK^T for tile it+1 is computed during iteration it; softmax+PV consume the previous St.
// K triple-buffered (distance 2), V double-buffered (distance 1). LDS 84KB, 1 block/CU.
// St ping-pong via 2x-unrolled loop (static array names, no runtime indexing).
__global__ __launch_bounds__(512, 2) void attn_kernel(
    const u16* __restrict__ Q, const u16* __restrict__ K, const u16* __restrict__ Vt,
    u16* __restrict__ Oattn) {
  // K: 3 bufs x 2 kv-halves x 4096 u16 (8KB tiles) = 48KB; V: 2 x 2 x 4096 = 32KB.
  __shared__ __align__(16) u16 KVs[40960];
  __shared__ float Lsc2[1024];

  const int t = threadIdx.x;
  const int wave = t >> 6, lane = t & 63;
  const int r = lane & 15, qd = lane >> 4;
  const int g = wave >> 1, kv = wave & 1;

  // XCD-aware remap (bijective, 256 blocks % 8 XCDs == 0): XCD x owns bh {2x, 2x+1}.
  const int flat = blockIdx.y * 16 + blockIdx.x;
  const int xcd = flat & 7, idx = flat >> 3;
  const int bh = xcd * 2 + (idx >> 4);
  const int qi = idx & 15;
  const int b = bh >> 3, h = bh & 7;
  const long bbase = (long)b * 4096 * 512;
  const int q0 = qi * 256;

  const int sw = r & 7;
  const int ck0 = (qd ^ sw) * 8;
  const int ck1 = ((qd + 4) ^ sw) * 8;
  int vof0[2], vof1[2];
#pragma unroll
  for (int c = 0; c < 2; c++) {
    vof0[c] = ((c * 4 + (qd >> 1)) ^ sw) * 8 + 4 * (qd & 1);
    vof1[c] = ((c * 4 + 2 + (qd >> 1)) ^ sw) * 8 + 4 * (qd & 1);
  }

  bf16x8_t ones8;
#pragma unroll
  for (int j = 0; j < 8; j++) ones8[j] = (__bf16)1.0f;

  bf16x8_t qf[4][2];
#pragma unroll
  for (int qa = 0; qa < 4; qa++) {
    const u16* qp = Q + bbase + (long)(q0 + g * 64 + qa * 16 + r) * 512 + h * 64 + qd * 8;
    qf[qa][0] = *(const bf16x8_t*)(qp);
    qf[qa][1] = *(const bf16x8_t*)(qp + 32);
  }

  f32x4_t accO[4][4];
  f32x4_t accL[4];
#pragma unroll
  for (int qa = 0; qa < 4; qa++) {
    f32x4_t z = {0.f, 0.f, 0.f, 0.f};
    accL[qa] = z;
#pragma unroll
    for (int nt = 0; nt < 4; nt++) accO[qa][nt] = z;
  }

  const int rr = lane >> 3;
  const int cc = (lane & 7) ^ rr;
  const u16* kgb = K + bbase + (long)(kv * 2048 + g * 16 + rr) * 512 + h * 64 + cc * 8;
  const u16* vgb = Vt + ((long)(b * 512 + h * 64 + g * 16 + rr)) * 4096 + kv * 2048 + cc * 8;
  // per-wave LDS staging bases (linear dest for gl_lds)
  u16* kst = KVs + kv * 4096 + g * 1024;           // + kbuf*8192
  u16* vst = KVs + 24576 + kv * 4096 + g * 1024;   // + vbuf*8192
  const u16* krd = KVs + kv * 4096;                // + kbuf*8192
  const u16* vrd = KVs + 24576 + kv * 4096;        // + vbuf*8192

  // prologue: K0 -> kbuf0, K1 -> kbuf1, V0 -> vbuf0
#pragma unroll
  for (int i = 0; i < 2; i++) gl_lds16(kgb + (long)i * 8 * 512, kst + i * 512);
#pragma unroll
  for (int i = 0; i < 2; i++) gl_lds16(kgb + (long)(64 + i * 8) * 512, kst + 8192 + i * 512);
#pragma unroll
  for (int i = 0; i < 2; i++) gl_lds16(vgb + (long)i * 8 * 4096, vst + i * 512);
  __syncthreads();

  f32x4_t Sa[4][4], Sb[4][4];

  // QK0 from kbuf 0 -> Sa
  __builtin_amdgcn_s_setprio(1);
#pragma unroll
  for (int nt = 0; nt < 4; nt++) {
    const u16* kb = krd + (nt * 16 + r) * 64;
    bf16x8_t kf0 = *(const bf16x8_t*)(kb + ck0);
    bf16x8_t kf1 = *(const bf16x8_t*)(kb + ck1);
#pragma unroll
    for (int qa = 0; qa < 4; qa++) {
      f32x4_t z = {0.f, 0.f, 0.f, 0.f};
      z = mfma16(kf0, qf[qa][0], z);
      z = mfma16(kf1, qf[qa][1], z);
      Sa[qa][nt] = z;
    }
  }
  __builtin_amdgcn_s_setprio(0);

  int kr = 1, kw = 2;  // K buffer being read for QK_{it+1} / written for K_{it+2}

  auto body = [&](int it, f32x4_t (&Sp)[4][4], f32x4_t (&Sn)[4][4]) {
    // prefetch K_{it+2}, V_{it+1}
    if (it < 30) {
      const long ko = (long)(it + 2) * 64;
      u16* kd = kst + kw * 8192;
#pragma unroll
      for (int i = 0; i < 2; i++) gl_lds16(kgb + (ko + i * 8) * 512, kd + i * 512);
    }
    if (it < 31) {
      const long vo = (long)(it + 1) * 64;
      u16* vd = vst + ((it + 1) & 1) * 8192;
#pragma unroll
      for (int i = 0; i < 2; i++) gl_lds16(vgb + vo + (long)i * 8 * 4096, vd + i * 512);
    }
    // QK^T for tile it+1 (results consumed next iteration -> latency off critical path)
    if (it < 31) {
      const u16* kbb = krd + kr * 8192;
      __builtin_amdgcn_s_setprio(1);
#pragma unroll
      for (int nt = 0; nt < 4; nt++) {
        const u16* kb = kbb + (nt * 16 + r) * 64;
        bf16x8_t kf0 = *(const bf16x8_t*)(kb + ck0);
        bf16x8_t kf1 = *(const bf16x8_t*)(kb + ck1);
#pragma unroll
        for (int qa = 0; qa < 4; qa++) {
          f32x4_t z = {0.f, 0.f, 0.f, 0.f};
          z = mfma16(kf0, qf[qa][0], z);
          z = mfma16(kf1, qf[qa][1], z);
          Sn[qa][nt] = z;
        }
      }
      __builtin_amdgcn_s_setprio(0);
    }
    // softmax(Sp) + PV for tile it
    const u16* vbb = vrd + (it & 1) * 8192;
#pragma unroll
    for (int c = 0; c < 2; c++) {
      bf16x8_t pf[4];
#pragma unroll
      for (int qa = 0; qa < 4; qa++) {
        f32x4_t e0, e1;
#pragma unroll
        for (int j = 0; j < 4; j++) {
          e0[j] = __builtin_amdgcn_exp2f(Sp[qa][2 * c][j]);
          e1[j] = __builtin_amdgcn_exp2f(Sp[qa][2 * c + 1][j]);
        }
        bf16x4_t b0 = __builtin_convertvector(e0, bf16x4_t);
        bf16x4_t b1 = __builtin_convertvector(e1, bf16x4_t);
        bf16x8_t p8;
#pragma unroll
        for (int j = 0; j < 4; j++) { p8[j] = b0[j]; p8[4 + j] = b1[j]; }
        pf[qa] = p8;
      }
#pragma unroll
      for (int qa = 0; qa < 4; qa++) accL[qa] = mfma16(ones8, pf[qa], accL[qa]);
      bf16x8_t va[4];
#pragma unroll
      for (int dm = 0; dm < 4; dm++) {
        const u16* vb = vbb + (dm * 16 + r) * 64;
        union { uint4 u; bf16x8_t v; } cat;
        *(uint2*)&cat.u.x = *(const uint2*)(vb + vof0[c]);
        *(uint2*)&cat.u.z = *(const uint2*)(vb + vof1[c]);
        va[dm] = cat.v;
      }
      __builtin_amdgcn_s_setprio(1);
#pragma unroll
      for (int qa = 0; qa < 4; qa++)
#pragma unroll
        for (int dm = 0; dm < 4; dm++)
          accO[qa][dm] = mfma16(va[dm], pf[qa], accO[qa][dm]);
      __builtin_amdgcn_s_setprio(0);
    }
    __syncthreads();
  };

  for (int it2 = 0; it2 < 32; it2 += 2) {
    body(it2, Sa, Sb);
    { int nk = 3 - kr - kw; kr = kw; kw = nk; }
    body(it2 + 1, Sb, Sa);
    { int nk = 3 - kr - kw; kr = kw; kw = nk; }
  }

  // ---------------- cross-kv combine + store (unchanged) ----------------
  float* Sc = (float*)KVs;  // 16384 floats, fits in 80KB K/V region
  if (kv == 1) {
#pragma unroll
    for (int qa = 0; qa < 4; qa++) {
#pragma unroll
      for (int dm = 0; dm < 4; dm++)
        *(f32x4_t*)&Sc[g * 4096 + ((qa * 4 + dm) * 64 + lane) * 4] = accO[qa][dm];
      Lsc2[g * 256 + qa * 64 + lane] = accL[qa][0];
    }
  }
  __syncthreads();
  if (kv == 0) {
#pragma unroll
    for (int qa = 0; qa < 4; qa++) {
      float L = accL[qa][0] + Lsc2[g * 256 + qa * 64 + lane];
      float inv = 1.f / L;
      int gq = q0 + g * 64 + qa * 16 + r;
#pragma unroll
      for (int dm = 0; dm < 4; dm++) {
        f32x4_t o = *(const f32x4_t*)&Sc[g * 4096 + ((qa * 4 + dm) * 64 + lane) * 4];
        o += accO[qa][dm];
        bf16x4_t ob;
#pragma unroll
        for (int reg = 0; reg < 4; reg++) ob[reg] = (__bf16)(o[reg] * inv);
        *(uint2*)&Oattn[bbase + (long)gq * 512 + h * 64 + dm * 16 + qd * 4] = *(uint2*)&ob;
      }
    }
  }
}

// ---------------- launch ----------------
extern "C" void kernel_launch(void* const* d_in, const int* in_sizes, int n_in,
                              void* d_out, int out_size, void* d_ws, size_t ws_size,
                              hipStream_t stream) {
  const float* x  = (const float*)d_in[0];
  const float* Wq = (const float*)d_in[1];
  const float* Wk = (const float*)d_in[2];
  const float* Wv = (const float*)d_in[3];
  const float* Wo = (const float*)d_in[4];
  const float* bo = (const float*)d_in[5];
  float* out = (float*)d_out;

  u16* ws  = (u16*)d_ws;
  u16* Qb  = ws;
  u16* Kb  = Qb  + 4194304;
  u16* Vtg = Kb  + 4194304;   // V^T: [2*512][4096]
  u16* Ab  = Vtg + 4194304;
  u16* Xb  = Ab;              // aliased: Xb live [cast, qkv); Ab live [attn, out) — disjoint
  u16* Wqb = Ab  + 4194304;
  u16* Wkb = Wqb + 262144;
  u16* Wvb = Wkb + 262144;
  u16* Wob = Wvb + 262144;

  cast_kernel<<<2560, 256, 0, stream>>>(x, Wq, Wk, Wv, Wo, Xb, Wqb, Wkb, Wvb, Wob);

  dim3 g1(64, 4, 3);
  gemm_qkv_kernel<<<g1, 256, 0, stream>>>(Xb, Wqb, Wkb, Wvb, Qb, Kb, Vtg);

  dim3 g2(16, 16);
  attn_kernel<<<g2, 512, 0, stream>>>(Qb, Kb, Vtg, Ab);

  dim3 g3(64, 4);
  gemm_out_kernel<<<g3, 256, 0, stream>>>(Ab, Wob, out, bo);
}

// Round 5
// 199.468 us; speedup vs baseline: 1.5467x; 1.5467x over previous
//
#include <hip/hip_runtime.h>

// Problem constants: B=2, S=4096, H=8, DH=64, D=512, M = B*S = 8192.
#define LOG2E 1.44269504088896340736f

typedef unsigned short u16;
typedef __bf16 bf16x4_t __attribute__((ext_vector_type(4)));
typedef __bf16 bf16x8_t __attribute__((ext_vector_type(8)));
typedef float f32x4_t __attribute__((ext_vector_type(4)));

__device__ __forceinline__ f32x4_t mfma16(bf16x8_t a, bf16x8_t b, f32x4_t c) {
  return __builtin_amdgcn_mfma_f32_16x16x32_bf16(a, b, c, 0, 0, 0);
}

// async 16B global -> LDS (dest = wave-uniform base + lane*16)
__device__ __forceinline__ void gl_lds16(const u16* g, u16* l) {
  __builtin_amdgcn_global_load_lds(
      (const __attribute__((address_space(1))) unsigned int*)g,
      (__attribute__((address_space(3))) unsigned int*)l, 16, 0, 0);
}

// ---------------- one-shot cast: fp32 -> bf16 (Wq pre-scaled by 0.125*log2e) --------------
__global__ __launch_bounds__(256) void cast_kernel(
    const float* __restrict__ x, const float* __restrict__ Wq, const float* __restrict__ Wk,
    const float* __restrict__ Wv, const float* __restrict__ Wo,
    u16* __restrict__ Xb, u16* __restrict__ Wqb, u16* __restrict__ Wkb,
    u16* __restrict__ Wvb, u16* __restrict__ Wob) {
  const int bid = blockIdx.x;
  const float* src;
  u16* dst;
  float scale = 1.f;
  int rel;
  if (bid < 2048)      { src = x;  dst = Xb;  rel = bid; }
  else if (bid < 2176) { src = Wq; dst = Wqb; rel = bid - 2048; scale = 0.125f * LOG2E; }
  else if (bid < 2304) { src = Wk; dst = Wkb; rel = bid - 2176; }
  else if (bid < 2432) { src = Wv; dst = Wvb; rel = bid - 2304; }
  else                 { src = Wo; dst = Wob; rel = bid - 2432; }
  const int i = rel * 2048 + threadIdx.x * 8;
  f32x4_t a = *(const f32x4_t*)(src + i) * scale;
  f32x4_t b = *(const f32x4_t*)(src + i + 4) * scale;
  union { uint4 u; struct { bf16x4_t lo, hi; } s; } c;
  c.s.lo = __builtin_convertvector(a, bf16x4_t);
  c.s.hi = __builtin_convertvector(b, bf16x4_t);
  *(uint4*)(dst + i) = c.u;
}

// ---------------- bf16 GEMM core (unchanged from round 3) --------------------------------
template <int MODE>
__device__ __forceinline__ void gemm_core_bf16(const u16* __restrict__ A, const u16* __restrict__ Bt,
                                               void* __restrict__ Cout, const float* __restrict__ bo,
                                               int Mbase, int Nbase) {
  __shared__ __align__(16) u16 smem[128 * 128];
  u16 (*As)[64] = (u16(*)[64])smem;
  u16 (*Bs)[64] = (u16(*)[64])(smem + 128 * 64);
  const int t = threadIdx.x;
  const int wave = t >> 6, lane = t & 63;
  const int r = lane & 15, qd = lane >> 4;
  const int wm = wave & 1, wn = wave >> 1;
  const int rr = lane >> 3;
  const int s8 = ((lane & 7) ^ (rr & 7)) * 8;

  f32x4_t acc[4][4];
#pragma unroll
  for (int i = 0; i < 4; i++)
#pragma unroll
    for (int j = 0; j < 4; j++) { f32x4_t z = {0.f, 0.f, 0.f, 0.f}; acc[i][j] = z; }

  const u16* pa = A  + (Mbase + wave * 32 + rr) * 512 + s8;
  const u16* pb = Bt + (Nbase + wave * 32 + rr) * 512 + s8;
  u16* la = &As[wave * 32][0];
  u16* lb = &Bs[wave * 32][0];

  for (int k0 = 0; k0 < 512; k0 += 64) {
#pragma unroll
    for (int j = 0; j < 4; j++) gl_lds16(pa + k0 + j * 8 * 512, la + j * 8 * 64);
#pragma unroll
    for (int j = 0; j < 4; j++) gl_lds16(pb + k0 + j * 8 * 512, lb + j * 8 * 64);
    __syncthreads();
#pragma unroll
    for (int h = 0; h < 2; h++) {
      bf16x8_t af[4], bfr[4];
#pragma unroll
      for (int i = 0; i < 4; i++)
        af[i]  = *(const bf16x8_t*)&As[wm * 64 + i * 16 + r][((h * 4 + qd) ^ (r & 7)) * 8];
#pragma unroll
      for (int j = 0; j < 4; j++)
        bfr[j] = *(const bf16x8_t*)&Bs[wn * 64 + j * 16 + r][((h * 4 + qd) ^ (r & 7)) * 8];
#pragma unroll
      for (int i = 0; i < 4; i++)
#pragma unroll
        for (int j = 0; j < 4; j++) acc[i][j] = mfma16(af[i], bfr[j], acc[i][j]);
    }
    __syncthreads();
  }

  if (MODE != 2) {
#pragma unroll
    for (int i = 0; i < 4; i++)
#pragma unroll
      for (int j = 0; j < 4; j++)
#pragma unroll
        for (int reg = 0; reg < 4; reg++) {
          int row = wm * 64 + i * 16 + qd * 4 + reg;
          int col = wn * 64 + j * 16 + r;
          __bf16 bv = (__bf16)acc[i][j][reg];
          smem[row * 128 + (col ^ (((row >> 2) & 7) << 3))] = *(u16*)&bv;
        }
    __syncthreads();
#pragma unroll
    for (int p = 0; p < 8; p++) {
      int row = p * 16 + (t >> 4);
      int col = (t & 15) * 8;
      uint4 v = *(const uint4*)&smem[row * 128 + (col ^ (((row >> 2) & 7) << 3))];
      if (MODE == 0) {
        *(uint4*)&((u16*)Cout)[(Mbase + row) * 512 + Nbase + col] = v;
      } else {
        int bb = Nbase >> 12;
        int ss = (Nbase & 4095) + col;
        *(uint4*)&((u16*)Cout)[((long)(bb * 512 + Mbase + row)) * 4096 + ss] = v;
      }
    }
  } else {
    float* stf = (float*)smem;
    float bv[4];
#pragma unroll
    for (int j = 0; j < 4; j++) bv[j] = bo[Nbase + wn * 64 + j * 16 + r];
#pragma unroll
    for (int hh = 0; hh < 2; hh++) {
      __syncthreads();
      if (wm == hh) {
#pragma unroll
        for (int i = 0; i < 4; i++)
#pragma unroll
          for (int j = 0; j < 4; j++)
#pragma unroll
            for (int reg = 0; reg < 4; reg++) {
              int row = i * 16 + qd * 4 + reg;
              int col = wn * 64 + j * 16 + r;
              stf[row * 128 + (col ^ (((row >> 2) & 7) << 2))] = acc[i][j][reg] + bv[j];
            }
      }
      __syncthreads();
#pragma unroll
      for (int p = 0; p < 4; p++) {
        int row = p * 16 + (t >> 4);
        int col = (t & 15) * 8;
        f32x4_t v0 = *(const f32x4_t*)&stf[row * 128 + ((col) ^ (((row >> 2) & 7) << 2))];
        f32x4_t v1 = *(const f32x4_t*)&stf[row * 128 + ((col + 4) ^ (((row >> 2) & 7) << 2))];
        *(f32x4_t*)&((float*)Cout)[(Mbase + hh * 64 + row) * 512 + Nbase + col] = v0;
        *(f32x4_t*)&((float*)Cout)[(Mbase + hh * 64 + row) * 512 + Nbase + col + 4] = v1;
      }
    }
  }
}

__global__ __launch_bounds__(256) void gemm_qkv_kernel(
    const u16* __restrict__ Xb,
    const u16* __restrict__ Wqb, const u16* __restrict__ Wkb, const u16* __restrict__ Wvb,
    u16* __restrict__ Q, u16* __restrict__ K, u16* __restrict__ Vt) {
  if (blockIdx.z == 0)
    gemm_core_bf16<0>(Xb, Wqb, Q, nullptr, blockIdx.x * 128, blockIdx.y * 128);
  else if (blockIdx.z == 1)
    gemm_core_bf16<0>(Xb, Wkb, K, nullptr, blockIdx.x * 128, blockIdx.y * 128);
  else  // V^T = Wv @ X^T
    gemm_core_bf16<1>(Wvb, Xb, Vt, nullptr, blockIdx.y * 128, blockIdx.x * 128);
}

__global__ __launch_bounds__(256) void gemm_out_kernel(
    const u16* __restrict__ Aat, const u16* __restrict__ Wob,
    float* __restrict__ Out, const float* __restrict__ bo) {
  gemm_core_bf16<2>(Aat, Wob, Out, bo, blockIdx.x * 128, blockIdx.y * 128);
}

// ---------------- flash attention v10: high-occupancy (4 waves/SIMD) ----------------------
// 1024 blocks x 4 waves (QBLK=64: 2 g-halves of 32 q rows; kv split of KVBLK=64 keys).
// LDS 33KB -> 4 blocks/CU = 16 waves/CU. Double-buffered K/V (8KB/buf pair).
// K LDS: [kv][buf][key row 0..31][64 dh], slot^=(row&7). V LDS: [kv][buf][d%32][dual-d rows:
// slot s_g = (d>=32)*4 + keyslot, stored at slot s_g^(row&7)].
__global__ __launch_bounds__(256, 4) void attn_kernel(
    const u16* __restrict__ Q, const u16* __restrict__ K, const u16* __restrict__ Vt,
    u16* __restrict__ Oattn) {
  __shared__ __align__(16) u16 KVs[16384];  // 32KB: K [0,8192), V [8192,16384)
  __shared__ float Lsc2[256];

  const int t = threadIdx.x;
  const int wave = t >> 6, lane = t & 63;
  const int r = lane & 15, qd = lane >> 4;
  const int g = wave >> 1, kv = wave & 1;

  // XCD-aware remap (bijective, 1024 % 8 == 0): XCD x owns bh {2x, 2x+1}.
  const int flat = blockIdx.y * 64 + blockIdx.x;
  const int xcd = flat & 7, idx = flat >> 3;  // idx 0..127
  const int bh = xcd * 2 + (idx >> 6);
  const int qi = idx & 63;
  const int b = bh >> 3, h = bh & 7;
  const long bbase = (long)b * 4096 * 512;
  const int q0 = qi * 64;

  const int sw = r & 7;
  const int ck0 = (qd ^ sw) * 8;
  const int ck1 = ((qd + 4) ^ sw) * 8;
  // V read offsets: dm-half dh (dm>>1) selects slot-group; two 8B chunks per fragment
  int vo0[2], vo1[2];
#pragma unroll
  for (int dh2 = 0; dh2 < 2; dh2++) {
    vo0[dh2] = (((dh2 * 4 + (qd >> 1))) ^ sw) * 8 + (qd & 1) * 4;
    vo1[dh2] = (((dh2 * 4 + 2 + (qd >> 1))) ^ sw) * 8 + (qd & 1) * 4;
  }

  bf16x8_t ones8;
#pragma unroll
  for (int j = 0; j < 8; j++) ones8[j] = (__bf16)1.0f;

  bf16x8_t qf[2][2];
#pragma unroll
  for (int qa = 0; qa < 2; qa++) {
    const u16* qp = Q + bbase + (long)(q0 + g * 32 + qa * 16 + r) * 512 + h * 64 + qd * 8;
    qf[qa][0] = *(const bf16x8_t*)(qp);
    qf[qa][1] = *(const bf16x8_t*)(qp + 32);
  }

  f32x4_t accO[2][4];
  f32x4_t accL[2];
#pragma unroll
  for (int qa = 0; qa < 2; qa++) {
    f32x4_t z = {0.f, 0.f, 0.f, 0.f};
    accL[qa] = z;
#pragma unroll
    for (int dm = 0; dm < 4; dm++) accO[qa][dm] = z;
  }

  // staging source pointers (pre-swizzled global slots; linear LDS dest)
  const int rr = lane >> 3;
  const int cc = lane & 7;
  const int sg = cc ^ rr;
  const u16* kgb = K + bbase + (long)(kv * 32 + g * 16 + rr) * 512 + h * 64 + sg * 8;
  const u16* vgb = Vt + ((long)(b * 512 + h * 64 + (sg >> 2) * 32 + g * 16 + rr)) * 4096 +
                   kv * 32 + (sg & 3) * 8;
  u16* kst = KVs + kv * 4096 + g * 1024;          // + buf*2048, + i*512
  u16* vst = KVs + 8192 + kv * 4096 + g * 1024;   // + buf*2048, + i*512
  const u16* krd = KVs + kv * 4096;               // + buf*2048
  const u16* vrd = KVs + 8192 + kv * 4096;        // + buf*2048

  // prologue: stage tile 0 into buf 0
#pragma unroll
  for (int i = 0; i < 2; i++) gl_lds16(kgb + (long)i * 8 * 512, kst + i * 512);
#pragma unroll
  for (int i = 0; i < 2; i++) gl_lds16(vgb + (long)i * 8 * 4096, vst + i * 512);

  for (int it = 0; it < 64; it++) {
    const int buf = it & 1;
    __syncthreads();

    if (it < 63) {
      const int nb = (it + 1) & 1;
      const long ko = (long)(it + 1) * 64;
#pragma unroll
      for (int i = 0; i < 2; i++)
        gl_lds16(kgb + (ko + i * 8) * 512, kst + nb * 2048 + i * 512);
#pragma unroll
      for (int i = 0; i < 2; i++)
        gl_lds16(vgb + ko + (long)i * 8 * 4096, vst + nb * 2048 + i * 512);
    }

    bf16x8_t kf[2][2];
#pragma unroll
    for (int nt = 0; nt < 2; nt++) {
      const u16* kb = krd + buf * 2048 + (nt * 16 + r) * 64;
      kf[nt][0] = *(const bf16x8_t*)(kb + ck0);
      kf[nt][1] = *(const bf16x8_t*)(kb + ck1);
    }

    f32x4_t St[2][2];
    __builtin_amdgcn_s_setprio(1);
#pragma unroll
    for (int qa = 0; qa < 2; qa++)
#pragma unroll
      for (int nt = 0; nt < 2; nt++) {
        f32x4_t z = {0.f, 0.f, 0.f, 0.f};
        z = mfma16(kf[nt][0], qf[qa][0], z);
        z = mfma16(kf[nt][1], qf[qa][1], z);
        St[qa][nt] = z;
      }
    __builtin_amdgcn_s_setprio(0);

    bf16x8_t pf[2];
#pragma unroll
    for (int qa = 0; qa < 2; qa++) {
      f32x4_t e0, e1;
#pragma unroll
      for (int j = 0; j < 4; j++) {
        e0[j] = __builtin_amdgcn_exp2f(St[qa][0][j]);
        e1[j] = __builtin_amdgcn_exp2f(St[qa][1][j]);
      }
      bf16x4_t b0 = __builtin_convertvector(e0, bf16x4_t);
      bf16x4_t b1 = __builtin_convertvector(e1, bf16x4_t);
      bf16x8_t p8;
#pragma unroll
      for (int j = 0; j < 4; j++) { p8[j] = b0[j]; p8[4 + j] = b1[j]; }
      pf[qa] = p8;
    }

#pragma unroll
    for (int qa = 0; qa < 2; qa++) accL[qa] = mfma16(ones8, pf[qa], accL[qa]);

    bf16x8_t va[4];
#pragma unroll
    for (int dm = 0; dm < 4; dm++) {
      const u16* vb = vrd + buf * 2048 + ((dm & 1) * 16 + r) * 64;
      union { uint4 u; bf16x8_t v; } cat;
      *(uint2*)&cat.u.x = *(const uint2*)(vb + vo0[dm >> 1]);
      *(uint2*)&cat.u.z = *(const uint2*)(vb + vo1[dm >> 1]);
      va[dm] = cat.v;
    }
    __builtin_amdgcn_s_setprio(1);
#pragma unroll
    for (int qa = 0; qa < 2; qa++)
#pragma unroll
      for (int dm = 0; dm < 4; dm++)
        accO[qa][dm] = mfma16(va[dm], pf[qa], accO[qa][dm]);
    __builtin_amdgcn_s_setprio(0);
  }

  // ---------------- cross-kv combine + store ----------------
  __syncthreads();
  float* Sc = (float*)KVs;  // 8192 floats available; need 4096
  if (kv == 1) {
#pragma unroll
    for (int qa = 0; qa < 2; qa++) {
#pragma unroll
      for (int dm = 0; dm < 4; dm++)
        *(f32x4_t*)&Sc[g * 2048 + ((qa * 4 + dm) * 64 + lane) * 4] = accO[qa][dm];
      Lsc2[g * 128 + qa * 64 + lane] = accL[qa][0];
    }
  }
  __syncthreads();
  if (kv == 0) {
#pragma unroll
    for (int qa = 0; qa < 2; qa++) {
      float L = accL[qa][0] + Lsc2[g * 128 + qa * 64 + lane];
      float inv = 1.f / L;
      int gq = q0 + g * 32 + qa * 16 + r;
#pragma unroll
      for (int dm = 0; dm < 4; dm++) {
        f32x4_t o = *(const f32x4_t*)&Sc[g * 2048 + ((qa * 4 + dm) * 64 + lane) * 4];
        o += accO[qa][dm];
        bf16x4_t ob;
#pragma unroll
        for (int reg = 0; reg < 4; reg++) ob[reg] = (__bf16)(o[reg] * inv);
        *(uint2*)&Oattn[bbase + (long)gq * 512 + h * 64 + dm * 16 + qd * 4] = *(uint2*)&ob;
      }
    }
  }
}

// ---------------- launch ----------------
extern "C" void kernel_launch(void* const* d_in, const int* in_sizes, int n_in,
                              void* d_out, int out_size, void* d_ws, size_t ws_size,
                              hipStream_t stream) {
  const float* x  = (const float*)d_in[0];
  const float* Wq = (const float*)d_in[1];
  const float* Wk = (const float*)d_in[2];
  const float* Wv = (const float*)d_in[3];
  const float* Wo = (const float*)d_in[4];
  const float* bo = (const float*)d_in[5];
  float* out = (float*)d_out;

  u16* ws  = (u16*)d_ws;
  u16* Qb  = ws;
  u16* Kb  = Qb  + 4194304;
  u16* Vtg = Kb  + 4194304;   // V^T: [2*512][4096]
  u16* Ab  = Vtg + 4194304;
  u16* Xb  = Ab;              // aliased: Xb live [cast, qkv); Ab live [attn, out) — disjoint
  u16* Wqb = Ab  + 4194304;
  u16* Wkb = Wqb + 262144;
  u16* Wvb = Wkb + 262144;
  u16* Wob = Wvb + 262144;

  cast_kernel<<<2560, 256, 0, stream>>>(x, Wq, Wk, Wv, Wo, Xb, Wqb, Wkb, Wvb, Wob);

  dim3 g1(64, 4, 3);
  gemm_qkv_kernel<<<g1, 256, 0, stream>>>(Xb, Wqb, Wkb, Wvb, Qb, Kb, Vtg);

  dim3 g2(64, 16);
  attn_kernel<<<g2, 256, 0, stream>>>(Qb, Kb, Vtg, Ab);

  dim3 g3(64, 4);
  gemm_out_kernel<<<g3, 256, 0, stream>>>(Ab, Wob, out, bo);
}

// Round 7
// 195.344 us; speedup vs baseline: 1.5793x; 1.0211x over previous
//
#include <hip/hip_runtime.h>

// Problem constants: B=2, S=4096, H=8, DH=64, D=512, M = B*S = 8192.
#define LOG2E 1.44269504088896340736f

typedef unsigned short u16;
typedef __bf16 bf16x4_t __attribute__((ext_vector_type(4)));
typedef __bf16 bf16x8_t __attribute__((ext_vector_type(8)));
typedef float f32x4_t __attribute__((ext_vector_type(4)));

__device__ __forceinline__ f32x4_t mfma16(bf16x8_t a, bf16x8_t b, f32x4_t c) {
  return __builtin_amdgcn_mfma_f32_16x16x32_bf16(a, b, c, 0, 0, 0);
}

// async 16B global -> LDS (dest = wave-uniform base + lane*16)
__device__ __forceinline__ void gl_lds16(const u16* g, u16* l) {
  __builtin_amdgcn_global_load_lds(
      (const __attribute__((address_space(1))) unsigned int*)g,
      (__attribute__((address_space(3))) unsigned int*)l, 16, 0, 0);
}

// ---------------- one-shot cast: fp32 -> bf16 (Wq pre-scaled by 0.125*log2e) --------------
__global__ __launch_bounds__(256) void cast_kernel(
    const float* __restrict__ x, const float* __restrict__ Wq, const float* __restrict__ Wk,
    const float* __restrict__ Wv, const float* __restrict__ Wo,
    u16* __restrict__ Xb, u16* __restrict__ Wqb, u16* __restrict__ Wkb,
    u16* __restrict__ Wvb, u16* __restrict__ Wob) {
  const int bid = blockIdx.x;
  const float* src;
  u16* dst;
  float scale = 1.f;
  int rel;
  if (bid < 2048)      { src = x;  dst = Xb;  rel = bid; }
  else if (bid < 2176) { src = Wq; dst = Wqb; rel = bid - 2048; scale = 0.125f * LOG2E; }
  else if (bid < 2304) { src = Wk; dst = Wkb; rel = bid - 2176; }
  else if (bid < 2432) { src = Wv; dst = Wvb; rel = bid - 2304; }
  else                 { src = Wo; dst = Wob; rel = bid - 2432; }
  const int i = rel * 2048 + threadIdx.x * 8;
  f32x4_t a = *(const f32x4_t*)(src + i) * scale;
  f32x4_t b = *(const f32x4_t*)(src + i + 4) * scale;
  union { uint4 u; struct { bf16x4_t lo, hi; } s; } c;
  c.s.lo = __builtin_convertvector(a, bf16x4_t);
  c.s.hi = __builtin_convertvector(b, bf16x4_t);
  *(uint4*)(dst + i) = c.u;
}

// ---------------- bf16 GEMM core (unchanged) ----------------------------------------------
template <int MODE>
__device__ __forceinline__ void gemm_core_bf16(const u16* __restrict__ A, const u16* __restrict__ Bt,
                                               void* __restrict__ Cout, const float* __restrict__ bo,
                                               int Mbase, int Nbase) {
  __shared__ __align__(16) u16 smem[128 * 128];
  u16 (*As)[64] = (u16(*)[64])smem;
  u16 (*Bs)[64] = (u16(*)[64])(smem + 128 * 64);
  const int t = threadIdx.x;
  const int wave = t >> 6, lane = t & 63;
  const int r = lane & 15, qd = lane >> 4;
  const int wm = wave & 1, wn = wave >> 1;
  const int rr = lane >> 3;
  const int s8 = ((lane & 7) ^ (rr & 7)) * 8;

  f32x4_t acc[4][4];
#pragma unroll
  for (int i = 0; i < 4; i++)
#pragma unroll
    for (int j = 0; j < 4; j++) { f32x4_t z = {0.f, 0.f, 0.f, 0.f}; acc[i][j] = z; }

  const u16* pa = A  + (Mbase + wave * 32 + rr) * 512 + s8;
  const u16* pb = Bt + (Nbase + wave * 32 + rr) * 512 + s8;
  u16* la = &As[wave * 32][0];
  u16* lb = &Bs[wave * 32][0];

  for (int k0 = 0; k0 < 512; k0 += 64) {
#pragma unroll
    for (int j = 0; j < 4; j++) gl_lds16(pa + k0 + j * 8 * 512, la + j * 8 * 64);
#pragma unroll
    for (int j = 0; j < 4; j++) gl_lds16(pb + k0 + j * 8 * 512, lb + j * 8 * 64);
    __syncthreads();
#pragma unroll
    for (int h = 0; h < 2; h++) {
      bf16x8_t af[4], bfr[4];
#pragma unroll
      for (int i = 0; i < 4; i++)
        af[i]  = *(const bf16x8_t*)&As[wm * 64 + i * 16 + r][((h * 4 + qd) ^ (r & 7)) * 8];
#pragma unroll
      for (int j = 0; j < 4; j++)
        bfr[j] = *(const bf16x8_t*)&Bs[wn * 64 + j * 16 + r][((h * 4 + qd) ^ (r & 7)) * 8];
#pragma unroll
      for (int i = 0; i < 4; i++)
#pragma unroll
        for (int j = 0; j < 4; j++) acc[i][j] = mfma16(af[i], bfr[j], acc[i][j]);
    }
    __syncthreads();
  }

  if (MODE != 2) {
#pragma unroll
    for (int i = 0; i < 4; i++)
#pragma unroll
      for (int j = 0; j < 4; j++)
#pragma unroll
        for (int reg = 0; reg < 4; reg++) {
          int row = wm * 64 + i * 16 + qd * 4 + reg;
          int col = wn * 64 + j * 16 + r;
          __bf16 bv = (__bf16)acc[i][j][reg];
          smem[row * 128 + (col ^ (((row >> 2) & 7) << 3))] = *(u16*)&bv;
        }
    __syncthreads();
#pragma unroll
    for (int p = 0; p < 8; p++) {
      int row = p * 16 + (t >> 4);
      int col = (t & 15) * 8;
      uint4 v = *(const uint4*)&smem[row * 128 + (col ^ (((row >> 2) & 7) << 3))];
      if (MODE == 0) {
        *(uint4*)&((u16*)Cout)[(Mbase + row) * 512 + Nbase + col] = v;
      } else {
        int bb = Nbase >> 12;
        int ss = (Nbase & 4095) + col;
        *(uint4*)&((u16*)Cout)[((long)(bb * 512 + Mbase + row)) * 4096 + ss] = v;
      }
    }
  } else {
    float* stf = (float*)smem;
    float bv[4];
#pragma unroll
    for (int j = 0; j < 4; j++) bv[j] = bo[Nbase + wn * 64 + j * 16 + r];
#pragma unroll
    for (int hh = 0; hh < 2; hh++) {
      __syncthreads();
      if (wm == hh) {
#pragma unroll
        for (int i = 0; i < 4; i++)
#pragma unroll
          for (int j = 0; j < 4; j++)
#pragma unroll
            for (int reg = 0; reg < 4; reg++) {
              int row = i * 16 + qd * 4 + reg;
              int col = wn * 64 + j * 16 + r;
              stf[row * 128 + (col ^ (((row >> 2) & 7) << 2))] = acc[i][j][reg] + bv[j];
            }
      }
      __syncthreads();
#pragma unroll
      for (int p = 0; p < 4; p++) {
        int row = p * 16 + (t >> 4);
        int col = (t & 15) * 8;
        f32x4_t v0 = *(const f32x4_t*)&stf[row * 128 + ((col) ^ (((row >> 2) & 7) << 2))];
        f32x4_t v1 = *(const f32x4_t*)&stf[row * 128 + ((col + 4) ^ (((row >> 2) & 7) << 2))];
        *(f32x4_t*)&((float*)Cout)[(Mbase + hh * 64 + row) * 512 + Nbase + col] = v0;
        *(f32x4_t*)&((float*)Cout)[(Mbase + hh * 64 + row) * 512 + Nbase + col + 4] = v1;
      }
    }
  }
}

__global__ __launch_bounds__(256) void gemm_qkv_kernel(
    const u16* __restrict__ Xb,
    const u16* __restrict__ Wqb, const u16* __restrict__ Wkb, const u16* __restrict__ Wvb,
    u16* __restrict__ Q, u16* __restrict__ K, u16* __restrict__ Vt) {
  if (blockIdx.z == 0)
    gemm_core_bf16<0>(Xb, Wqb, Q, nullptr, blockIdx.x * 128, blockIdx.y * 128);
  else if (blockIdx.z == 1)
    gemm_core_bf16<0>(Xb, Wkb, K, nullptr, blockIdx.x * 128, blockIdx.y * 128);
  else  // V^T = Wv @ X^T
    gemm_core_bf16<1>(Wvb, Xb, Vt, nullptr, blockIdx.y * 128, blockIdx.x * 128);
}

__global__ __launch_bounds__(256) void gemm_out_kernel(
    const u16* __restrict__ Aat, const u16* __restrict__ Wob,
    float* __restrict__ Out, const float* __restrict__ bo) {
  gemm_core_bf16<2>(Aat, Wob, Out, bo, blockIdx.x * 128, blockIdx.y * 128);
}

// ---------------- flash attention v11: half-tile software pipeline (no lambdas) -----------
// v8 shape: QBLK=256, 8 waves (g=0..3 q-group, kv=0..1 key-half), KVBLK=128 keys/iter.
// Each wave's 64-key tile split into sub0 (keys 0-31) / sub1 (32-63).
// HS0: QK(sub1,it)->Sy ; softmax+PV(sub0) from Sx.  HS1: QK(sub0,it+1)->Sx ; softmax+PV(sub1) from Sy.
// QK results consumed one half-step later -> MFMA overlaps the exp/pack VALU chain.
// K triple-buffered (48KB), V double-buffered (32KB); static array roles, no runtime reg indexing.
__global__ __launch_bounds__(512, 1) void attn_kernel(
    const u16* __restrict__ Q, const u16* __restrict__ K, const u16* __restrict__ Vt,
    u16* __restrict__ Oattn) {
  __shared__ __align__(16) u16 KVs[40960];  // K: [0,24576) 3 bufs x 8192; V: [24576,40960) 2 x 8192
  __shared__ float Lsc2[1024];

  const int t = threadIdx.x;
  const int wave = t >> 6, lane = t & 63;
  const int r = lane & 15, qd = lane >> 4;
  const int g = wave >> 1, kv = wave & 1;

  // XCD-aware remap (bijective, 256 blocks % 8 XCDs == 0): XCD x owns bh {2x, 2x+1}.
  const int flat = blockIdx.y * 16 + blockIdx.x;
  const int xcd = flat & 7, idx = flat >> 3;
  const int bh = xcd * 2 + (idx >> 4);
  const int qi = idx & 15;
  const int b = bh >> 3, h = bh & 7;
  const long bbase = (long)b * 4096 * 512;
  const int q0 = qi * 256;

  const int sw = r & 7;
  const int ck0 = (qd ^ sw) * 8;
  const int ck1 = ((qd + 4) ^ sw) * 8;
  int vof0[2], vof1[2];
#pragma unroll
  for (int c = 0; c < 2; c++) {
    vof0[c] = ((c * 4 + (qd >> 1)) ^ sw) * 8 + 4 * (qd & 1);
    vof1[c] = ((c * 4 + 2 + (qd >> 1)) ^ sw) * 8 + 4 * (qd & 1);
  }

  bf16x8_t ones8;
#pragma unroll
  for (int j = 0; j < 8; j++) ones8[j] = (__bf16)1.0f;

  bf16x8_t qf[4][2];
#pragma unroll
  for (int qa = 0; qa < 4; qa++) {
    const u16* qp = Q + bbase + (long)(q0 + g * 64 + qa * 16 + r) * 512 + h * 64 + qd * 8;
    qf[qa][0] = *(const bf16x8_t*)(qp);
    qf[qa][1] = *(const bf16x8_t*)(qp + 32);
  }

  f32x4_t accO[4][4];
  f32x4_t accL[4];
#pragma unroll
  for (int qa = 0; qa < 4; qa++) {
    f32x4_t z = {0.f, 0.f, 0.f, 0.f};
    accL[qa] = z;
#pragma unroll
    for (int dm = 0; dm < 4; dm++) accO[qa][dm] = z;
  }

  const int rr = lane >> 3;
  const int cc = (lane & 7) ^ rr;
  const u16* kgb = K + bbase + (long)(kv * 2048 + g * 16 + rr) * 512 + h * 64 + cc * 8;
  const u16* vgb = Vt + ((long)(b * 512 + h * 64 + g * 16 + rr)) * 4096 + kv * 2048 + cc * 8;
  u16* kst = KVs + kv * 4096 + g * 1024;           // + kbuf*8192
  u16* vst = KVs + 24576 + kv * 4096 + g * 1024;   // + vbuf*8192
  const u16* krd = KVs + kv * 4096;                // + kbuf*8192
  const u16* vrd = KVs + 24576 + kv * 4096;        // + vbuf*8192

  // prologue: K0 -> kbuf0, K1 -> kbuf1, V0 -> vbuf0
#pragma unroll
  for (int i = 0; i < 2; i++) gl_lds16(kgb + (long)i * 8 * 512, kst + i * 512);
#pragma unroll
  for (int i = 0; i < 2; i++) gl_lds16(kgb + (long)(64 + i * 8) * 512, kst + 8192 + i * 512);
#pragma unroll
  for (int i = 0; i < 2; i++) gl_lds16(vgb + (long)i * 8 * 4096, vst + i * 512);
  __syncthreads();

  f32x4_t Sx[4][2], Sy[4][2];

  // prologue QK: sub0 of tile 0 (kbuf 0) -> Sx
  __builtin_amdgcn_s_setprio(1);
#pragma unroll
  for (int nt2 = 0; nt2 < 2; nt2++) {
    const u16* kb = krd + (nt2 * 16 + r) * 64;
    bf16x8_t kf0 = *(const bf16x8_t*)(kb + ck0);
    bf16x8_t kf1 = *(const bf16x8_t*)(kb + ck1);
#pragma unroll
    for (int qa = 0; qa < 4; qa++) {
      f32x4_t z = {0.f, 0.f, 0.f, 0.f};
      z = mfma16(kf0, qf[qa][0], z);
      z = mfma16(kf1, qf[qa][1], z);
      Sx[qa][nt2] = z;
    }
  }
  __builtin_amdgcn_s_setprio(0);

  for (int it = 0; it < 32; ++it) {
    const int kb_cur = (it % 3) * 8192;
    const int kb_nxt = ((it + 1) % 3) * 8192;
    const int kb_stg = ((it + 2) % 3) * 8192;
    const int vb_cur = (it & 1) * 8192;
    const int vb_stg = ((it + 1) & 1) * 8192;

    __syncthreads();  // K[it+1], V[it] visible; staged-in-it-1 buffers safe to reuse

    if (it < 30) {
      const long ko = (long)(it + 2) * 64;
#pragma unroll
      for (int i = 0; i < 2; i++) gl_lds16(kgb + (ko + i * 8) * 512, kst + kb_stg + i * 512);
    }
    if (it < 31) {
      const long vo = (long)(it + 1) * 64;
#pragma unroll
      for (int i = 0; i < 2; i++) gl_lds16(vgb + vo + (long)i * 8 * 4096, vst + vb_stg + i * 512);
    }

    // ================= HS0: QK(sub1, it) -> Sy ; softmax+PV(sub0) from Sx ================
    {
      const u16* kbb = krd + kb_cur;
      __builtin_amdgcn_s_setprio(1);
#pragma unroll
      for (int nt2 = 0; nt2 < 2; nt2++) {
        const u16* kb = kbb + ((2 + nt2) * 16 + r) * 64;
        bf16x8_t kf0 = *(const bf16x8_t*)(kb + ck0);
        bf16x8_t kf1 = *(const bf16x8_t*)(kb + ck1);
#pragma unroll
        for (int qa = 0; qa < 4; qa++) {
          f32x4_t z = {0.f, 0.f, 0.f, 0.f};
          z = mfma16(kf0, qf[qa][0], z);
          z = mfma16(kf1, qf[qa][1], z);
          Sy[qa][nt2] = z;
        }
      }
      __builtin_amdgcn_s_setprio(0);

      bf16x8_t pf[4];
#pragma unroll
      for (int qa = 0; qa < 4; qa++) {
        f32x4_t e0, e1;
#pragma unroll
        for (int j = 0; j < 4; j++) {
          e0[j] = __builtin_amdgcn_exp2f(Sx[qa][0][j]);
          e1[j] = __builtin_amdgcn_exp2f(Sx[qa][1][j]);
        }
        bf16x4_t b0 = __builtin_convertvector(e0, bf16x4_t);
        bf16x4_t b1 = __builtin_convertvector(e1, bf16x4_t);
        bf16x8_t p8;
#pragma unroll
        for (int j = 0; j < 4; j++) { p8[j] = b0[j]; p8[4 + j] = b1[j]; }
        pf[qa] = p8;
      }
#pragma unroll
      for (int qa = 0; qa < 4; qa++) accL[qa] = mfma16(ones8, pf[qa], accL[qa]);

      bf16x8_t va[4];
#pragma unroll
      for (int dm = 0; dm < 4; dm++) {
        const u16* vb = vrd + vb_cur + (dm * 16 + r) * 64;
        union { uint4 u; bf16x8_t v; } cat;
        *(uint2*)&cat.u.x = *(const uint2*)(vb + vof0[0]);
        *(uint2*)&cat.u.z = *(const uint2*)(vb + vof1[0]);
        va[dm] = cat.v;
      }
      __builtin_amdgcn_s_setprio(1);
#pragma unroll
      for (int qa = 0; qa < 4; qa++)
#pragma unroll
        for (int dm = 0; dm < 4; dm++)
          accO[qa][dm] = mfma16(va[dm], pf[qa], accO[qa][dm]);
      __builtin_amdgcn_s_setprio(0);
    }

    // ============ HS1: QK(sub0, it+1) -> Sx ; softmax+PV(sub1) from Sy ===================
    {
      if (it < 31) {
        const u16* kbb = krd + kb_nxt;
        __builtin_amdgcn_s_setprio(1);
#pragma unroll
        for (int nt2 = 0; nt2 < 2; nt2++) {
          const u16* kb = kbb + (nt2 * 16 + r) * 64;
          bf16x8_t kf0 = *(const bf16x8_t*)(kb + ck0);
          bf16x8_t kf1 = *(const bf16x8_t*)(kb + ck1);
#pragma unroll
          for (int qa = 0; qa < 4; qa++) {
            f32x4_t z = {0.f, 0.f, 0.f, 0.f};
            z = mfma16(kf0, qf[qa][0], z);
            z = mfma16(kf1, qf[qa][1], z);
            Sx[qa][nt2] = z;
          }
        }
        __builtin_amdgcn_s_setprio(0);
      }

      bf16x8_t pf[4];
#pragma unroll
      for (int qa = 0; qa < 4; qa++) {
        f32x4_t e0, e1;
#pragma unroll
        for (int j = 0; j < 4; j++) {
          e0[j] = __builtin_amdgcn_exp2f(Sy[qa][0][j]);
          e1[j] = __builtin_amdgcn_exp2f(Sy[qa][1][j]);
        }
        bf16x4_t b0 = __builtin_convertvector(e0, bf16x4_t);
        bf16x4_t b1 = __builtin_convertvector(e1, bf16x4_t);
        bf16x8_t p8;
#pragma unroll
        for (int j = 0; j < 4; j++) { p8[j] = b0[j]; p8[4 + j] = b1[j]; }
        pf[qa] = p8;
      }
#pragma unroll
      for (int qa = 0; qa < 4; qa++) accL[qa] = mfma16(ones8, pf[qa], accL[qa]);

      bf16x8_t va[4];
#pragma unroll
      for (int dm = 0; dm < 4; dm++) {
        const u16* vb = vrd + vb_cur + (dm * 16 + r) * 64;
        union { uint4 u; bf16x8_t v; } cat;
        *(uint2*)&cat.u.x = *(const uint2*)(vb + vof0[1]);
        *(uint2*)&cat.u.z = *(const uint2*)(vb + vof1[1]);
        va[dm] = cat.v;
      }
      __builtin_amdgcn_s_setprio(1);
#pragma unroll
      for (int qa = 0; qa < 4; qa++)
#pragma unroll
        for (int dm = 0; dm < 4; dm++)
          accO[qa][dm] = mfma16(va[dm], pf[qa], accO[qa][dm]);
      __builtin_amdgcn_s_setprio(0);
    }
  }

  // ---------------- cross-kv combine + store (v8's) ----------------
  __syncthreads();
  float* Sc = (float*)KVs;  // 16384 floats needed; 20480 available
  if (kv == 1) {
#pragma unroll
    for (int qa = 0; qa < 4; qa++) {
#pragma unroll
      for (int dm = 0; dm < 4; dm++)
        *(f32x4_t*)&Sc[g * 4096 + ((qa * 4 + dm) * 64 + lane) * 4] = accO[qa][dm];
      Lsc2[g * 256 + qa * 64 + lane] = accL[qa][0];
    }
  }
  __syncthreads();
  if (kv == 0) {
#pragma unroll
    for (int qa = 0; qa < 4; qa++) {
      float L = accL[qa][0] + Lsc2[g * 256 + qa * 64 + lane];
      float inv = 1.f / L;
      int gq = q0 + g * 64 + qa * 16 + r;
#pragma unroll
      for (int dm = 0; dm < 4; dm++) {
        f32x4_t o = *(const f32x4_t*)&Sc[g * 4096 + ((qa * 4 + dm) * 64 + lane) * 4];
        o += accO[qa][dm];
        bf16x4_t ob;
#pragma unroll
        for (int reg = 0; reg < 4; reg++) ob[reg] = (__bf16)(o[reg] * inv);
        *(uint2*)&Oattn[bbase + (long)gq * 512 + h * 64 + dm * 16 + qd * 4] = *(uint2*)&ob;
      }
    }
  }
}

// ---------------- launch ----------------
extern "C" void kernel_launch(void* const* d_in, const int* in_sizes, int n_in,
                              void* d_out, int out_size, void* d_ws, size_t ws_size,
                              hipStream_t stream) {
  const float* x  = (const float*)d_in[0];
  const float* Wq = (const float*)d_in[1];
  const float* Wk = (const float*)d_in[2];
  const float* Wv = (const float*)d_in[3];
  const float* Wo = (const float*)d_in[4];
  const float* bo = (const float*)d_in[5];
  float* out = (float*)d_out;

  u16* ws  = (u16*)d_ws;
  u16* Qb  = ws;
  u16* Kb  = Qb  + 4194304;
  u16* Vtg = Kb  + 4194304;   // V^T: [2*512][4096]
  u16* Ab  = Vtg + 4194304;
  u16* Xb  = Ab;              // aliased: Xb live [cast, qkv); Ab live [attn, out) — disjoint
  u16* Wqb = Ab  + 4194304;
  u16* Wkb = Wqb + 262144;
  u16* Wvb = Wkb + 262144;
  u16* Wob = Wvb + 262144;

  cast_kernel<<<2560, 256, 0, stream>>>(x, Wq, Wk, Wv, Wo, Xb, Wqb, Wkb, Wvb, Wob);

  dim3 g1(64, 4, 3);
  gemm_qkv_kernel<<<g1, 256, 0, stream>>>(Xb, Wqb, Wkb, Wvb, Qb, Kb, Vtg);

  dim3 g2(16, 16);
  attn_kernel<<<g2, 512, 0, stream>>>(Qb, Kb, Vtg, Ab);

  dim3 g3(64, 4);
  gemm_out_kernel<<<g3, 256, 0, stream>>>(Ab, Wob, out, bo);
}

// Round 8
// 180.210 us; speedup vs baseline: 1.7120x; 1.0840x over previous
//
#include <hip/hip_runtime.h>

// Problem constants: B=2, S=4096, H=8, DH=64, D=512, M = B*S = 8192.
#define LOG2E 1.44269504088896340736f

typedef unsigned short u16;
typedef __bf16 bf16x4_t __attribute__((ext_vector_type(4)));
typedef __bf16 bf16x8_t __attribute__((ext_vector_type(8)));
typedef float f32x4_t __attribute__((ext_vector_type(4)));

__device__ __forceinline__ f32x4_t mfma16(bf16x8_t a, bf16x8_t b, f32x4_t c) {
  return __builtin_amdgcn_mfma_f32_16x16x32_bf16(a, b, c, 0, 0, 0);
}

// async 16B global -> LDS (dest = wave-uniform base + lane*16)
__device__ __forceinline__ void gl_lds16(const u16* g, u16* l) {
  __builtin_amdgcn_global_load_lds(
      (const __attribute__((address_space(1))) unsigned int*)g,
      (__attribute__((address_space(3))) unsigned int*)l, 16, 0, 0);
}

// ---------------- one-shot cast: fp32 -> bf16 (Wq pre-scaled by 0.125*log2e) --------------
__global__ __launch_bounds__(256) void cast_kernel(
    const float* __restrict__ x, const float* __restrict__ Wq, const float* __restrict__ Wk,
    const float* __restrict__ Wv, const float* __restrict__ Wo,
    u16* __restrict__ Xb, u16* __restrict__ Wqb, u16* __restrict__ Wkb,
    u16* __restrict__ Wvb, u16* __restrict__ Wob) {
  const int bid = blockIdx.x;
  const float* src;
  u16* dst;
  float scale = 1.f;
  int rel;
  if (bid < 2048)      { src = x;  dst = Xb;  rel = bid; }
  else if (bid < 2176) { src = Wq; dst = Wqb; rel = bid - 2048; scale = 0.125f * LOG2E; }
  else if (bid < 2304) { src = Wk; dst = Wkb; rel = bid - 2176; }
  else if (bid < 2432) { src = Wv; dst = Wvb; rel = bid - 2304; }
  else                 { src = Wo; dst = Wob; rel = bid - 2432; }
  const int i = rel * 2048 + threadIdx.x * 8;
  f32x4_t a = *(const f32x4_t*)(src + i) * scale;
  f32x4_t b = *(const f32x4_t*)(src + i + 4) * scale;
  union { uint4 u; struct { bf16x4_t lo, hi; } s; } c;
  c.s.lo = __builtin_convertvector(a, bf16x4_t);
  c.s.hi = __builtin_convertvector(b, bf16x4_t);
  *(uint4*)(dst + i) = c.u;
}

// ---------------- fused QKV GEMM: stage X-tile once, MFMA against 3 resident W tiles ------
// grid (64,4), 512 threads (8 waves: 2 wm x 4 wn). LDS 64KB: As[128][64] + Bq/Bk/Bv[128][64].
// Per K-step: 8 gl_lds/thread, 48 MFMA/wave (3x the per-staging density of the split version).
// Epilogue: LDS-transpose per proj; V staged transposed so V^T store is coalesced along s.
__global__ __launch_bounds__(512) void gemm_qkv_fused(
    const u16* __restrict__ Xb,
    const u16* __restrict__ Wqb, const u16* __restrict__ Wkb, const u16* __restrict__ Wvb,
    u16* __restrict__ Q, u16* __restrict__ K, u16* __restrict__ Vt) {
  __shared__ __align__(16) u16 SM[32768];  // 64KB
  u16 (*As)[64] = (u16(*)[64])SM;
  u16 (*Bq)[64] = (u16(*)[64])(SM + 8192);
  u16 (*Bk)[64] = (u16(*)[64])(SM + 16384);
  u16 (*Bv)[64] = (u16(*)[64])(SM + 24576);
  const int t = threadIdx.x;
  const int wave = t >> 6, lane = t & 63;
  const int r = lane & 15, qd = lane >> 4;
  const int wm = wave & 1, wn = wave >> 1;  // 2 x 4 wave grid over the 128x128 tile
  const int rr = lane >> 3;
  const int s8 = ((lane & 7) ^ (rr & 7)) * 8;  // pre-swizzled global 16B slot
  const int Mbase = blockIdx.x * 128, Nbase = blockIdx.y * 128;

  f32x4_t acc[3][4][2];
#pragma unroll
  for (int w = 0; w < 3; w++)
#pragma unroll
    for (int i = 0; i < 4; i++)
#pragma unroll
      for (int j = 0; j < 2; j++) { f32x4_t z = {0.f, 0.f, 0.f, 0.f}; acc[w][i][j] = z; }

  const u16* pa = Xb  + (Mbase + wave * 16 + rr) * 512 + s8;
  const u16* pq = Wqb + (Nbase + wave * 16 + rr) * 512 + s8;
  const u16* pk = Wkb + (Nbase + wave * 16 + rr) * 512 + s8;
  const u16* pv = Wvb + (Nbase + wave * 16 + rr) * 512 + s8;
  u16* la = &As[wave * 16][0];
  u16* lq = &Bq[wave * 16][0];
  u16* lk = &Bk[wave * 16][0];
  u16* lv = &Bv[wave * 16][0];

  for (int k0 = 0; k0 < 512; k0 += 64) {
#pragma unroll
    for (int p = 0; p < 2; p++) {
      gl_lds16(pa + k0 + p * 8 * 512, la + p * 512);
      gl_lds16(pq + k0 + p * 8 * 512, lq + p * 512);
      gl_lds16(pk + k0 + p * 8 * 512, lk + p * 512);
      gl_lds16(pv + k0 + p * 8 * 512, lv + p * 512);
    }
    __syncthreads();
#pragma unroll
    for (int h = 0; h < 2; h++) {
      bf16x8_t af[4];
#pragma unroll
      for (int i = 0; i < 4; i++)
        af[i] = *(const bf16x8_t*)&As[wm * 64 + i * 16 + r][((h * 4 + qd) ^ (r & 7)) * 8];
      bf16x8_t fq[2], fk[2], fv[2];
#pragma unroll
      for (int j = 0; j < 2; j++) {
        fq[j] = *(const bf16x8_t*)&Bq[wn * 32 + j * 16 + r][((h * 4 + qd) ^ (r & 7)) * 8];
        fk[j] = *(const bf16x8_t*)&Bk[wn * 32 + j * 16 + r][((h * 4 + qd) ^ (r & 7)) * 8];
        fv[j] = *(const bf16x8_t*)&Bv[wn * 32 + j * 16 + r][((h * 4 + qd) ^ (r & 7)) * 8];
      }
#pragma unroll
      for (int i = 0; i < 4; i++)
#pragma unroll
        for (int j = 0; j < 2; j++) {
          acc[0][i][j] = mfma16(af[i], fq[j], acc[0][i][j]);
          acc[1][i][j] = mfma16(af[i], fk[j], acc[1][i][j]);
          acc[2][i][j] = mfma16(af[i], fv[j], acc[2][i][j]);
        }
    }
    __syncthreads();
  }

  // ---------------- epilogue: LDS-transpose, coalesced stores ----------------
  const int erow = t >> 4;        // 0..31
  const int ecol = (t & 15) * 8;  // 0..120
  // Q then K: row-major [M][512]
#pragma unroll
  for (int w = 0; w < 2; w++) {
    __syncthreads();
    u16* dst = (w == 0) ? Q : K;
#pragma unroll
    for (int i = 0; i < 4; i++)
#pragma unroll
      for (int j = 0; j < 2; j++)
#pragma unroll
        for (int reg = 0; reg < 4; reg++) {
          int row = wm * 64 + i * 16 + qd * 4 + reg;
          int col = wn * 32 + j * 16 + r;
          __bf16 bvv = (__bf16)acc[w][i][j][reg];
          SM[row * 128 + (col ^ (((row >> 2) & 7) << 3))] = *(u16*)&bvv;
        }
    __syncthreads();
#pragma unroll
    for (int p = 0; p < 4; p++) {
      int row = p * 32 + erow;
      uint4 v = *(const uint4*)&SM[row * 128 + (ecol ^ (((row >> 2) & 7) << 3))];
      *(uint4*)&dst[(Mbase + row) * 512 + Nbase + ecol] = v;
    }
  }
  // V: stage transposed ct[d][s] so the V^T store is coalesced along s
  __syncthreads();
#pragma unroll
  for (int i = 0; i < 4; i++)
#pragma unroll
    for (int j = 0; j < 2; j++)
#pragma unroll
      for (int reg = 0; reg < 4; reg++) {
        int srow = wm * 64 + i * 16 + qd * 4 + reg;  // s within tile
        int dcol = wn * 32 + j * 16 + r;             // d within tile
        __bf16 bvv = (__bf16)acc[2][i][j][reg];
        SM[dcol * 128 + (srow ^ (((dcol >> 2) & 7) << 3))] = *(u16*)&bvv;
      }
  __syncthreads();
  {
    const int bb = Mbase >> 12;
    const int smod = Mbase & 4095;
#pragma unroll
    for (int p = 0; p < 4; p++) {
      int d = p * 32 + erow;
      uint4 v = *(const uint4*)&SM[d * 128 + (ecol ^ (((d >> 2) & 7) << 3))];
      *(uint4*)&Vt[((long)(bb * 512 + Nbase + d)) * 4096 + smod + ecol] = v;
    }
  }
}

// ---------------- bf16 GEMM core (used for out-proj only) ---------------------------------
template <int MODE>
__device__ __forceinline__ void gemm_core_bf16(const u16* __restrict__ A, const u16* __restrict__ Bt,
                                               void* __restrict__ Cout, const float* __restrict__ bo,
                                               int Mbase, int Nbase) {
  __shared__ __align__(16) u16 smem[128 * 128];
  u16 (*As)[64] = (u16(*)[64])smem;
  u16 (*Bs)[64] = (u16(*)[64])(smem + 128 * 64);
  const int t = threadIdx.x;
  const int wave = t >> 6, lane = t & 63;
  const int r = lane & 15, qd = lane >> 4;
  const int wm = wave & 1, wn = wave >> 1;
  const int rr = lane >> 3;
  const int s8 = ((lane & 7) ^ (rr & 7)) * 8;

  f32x4_t acc[4][4];
#pragma unroll
  for (int i = 0; i < 4; i++)
#pragma unroll
    for (int j = 0; j < 4; j++) { f32x4_t z = {0.f, 0.f, 0.f, 0.f}; acc[i][j] = z; }

  const u16* pa = A  + (Mbase + wave * 32 + rr) * 512 + s8;
  const u16* pb = Bt + (Nbase + wave * 32 + rr) * 512 + s8;
  u16* la = &As[wave * 32][0];
  u16* lb = &Bs[wave * 32][0];

  for (int k0 = 0; k0 < 512; k0 += 64) {
#pragma unroll
    for (int j = 0; j < 4; j++) gl_lds16(pa + k0 + j * 8 * 512, la + j * 8 * 64);
#pragma unroll
    for (int j = 0; j < 4; j++) gl_lds16(pb + k0 + j * 8 * 512, lb + j * 8 * 64);
    __syncthreads();
#pragma unroll
    for (int h = 0; h < 2; h++) {
      bf16x8_t af[4], bfr[4];
#pragma unroll
      for (int i = 0; i < 4; i++)
        af[i]  = *(const bf16x8_t*)&As[wm * 64 + i * 16 + r][((h * 4 + qd) ^ (r & 7)) * 8];
#pragma unroll
      for (int j = 0; j < 4; j++)
        bfr[j] = *(const bf16x8_t*)&Bs[wn * 64 + j * 16 + r][((h * 4 + qd) ^ (r & 7)) * 8];
#pragma unroll
      for (int i = 0; i < 4; i++)
#pragma unroll
        for (int j = 0; j < 4; j++) acc[i][j] = mfma16(af[i], bfr[j], acc[i][j]);
    }
    __syncthreads();
  }

  if (MODE != 2) {
#pragma unroll
    for (int i = 0; i < 4; i++)
#pragma unroll
      for (int j = 0; j < 4; j++)
#pragma unroll
        for (int reg = 0; reg < 4; reg++) {
          int row = wm * 64 + i * 16 + qd * 4 + reg;
          int col = wn * 64 + j * 16 + r;
          __bf16 bv = (__bf16)acc[i][j][reg];
          smem[row * 128 + (col ^ (((row >> 2) & 7) << 3))] = *(u16*)&bv;
        }
    __syncthreads();
#pragma unroll
    for (int p = 0; p < 8; p++) {
      int row = p * 16 + (t >> 4);
      int col = (t & 15) * 8;
      uint4 v = *(const uint4*)&smem[row * 128 + (col ^ (((row >> 2) & 7) << 3))];
      if (MODE == 0) {
        *(uint4*)&((u16*)Cout)[(Mbase + row) * 512 + Nbase + col] = v;
      } else {
        int bb = Nbase >> 12;
        int ss = (Nbase & 4095) + col;
        *(uint4*)&((u16*)Cout)[((long)(bb * 512 + Mbase + row)) * 4096 + ss] = v;
      }
    }
  } else {
    float* stf = (float*)smem;
    float bv[4];
#pragma unroll
    for (int j = 0; j < 4; j++) bv[j] = bo[Nbase + wn * 64 + j * 16 + r];
#pragma unroll
    for (int hh = 0; hh < 2; hh++) {
      __syncthreads();
      if (wm == hh) {
#pragma unroll
        for (int i = 0; i < 4; i++)
#pragma unroll
          for (int j = 0; j < 4; j++)
#pragma unroll
            for (int reg = 0; reg < 4; reg++) {
              int row = i * 16 + qd * 4 + reg;
              int col = wn * 64 + j * 16 + r;
              stf[row * 128 + (col ^ (((row >> 2) & 7) << 2))] = acc[i][j][reg] + bv[j];
            }
      }
      __syncthreads();
#pragma unroll
      for (int p = 0; p < 4; p++) {
        int row = p * 16 + (t >> 4);
        int col = (t & 15) * 8;
        f32x4_t v0 = *(const f32x4_t*)&stf[row * 128 + ((col) ^ (((row >> 2) & 7) << 2))];
        f32x4_t v1 = *(const f32x4_t*)&stf[row * 128 + ((col + 4) ^ (((row >> 2) & 7) << 2))];
        *(f32x4_t*)&((float*)Cout)[(Mbase + hh * 64 + row) * 512 + Nbase + col] = v0;
        *(f32x4_t*)&((float*)Cout)[(Mbase + hh * 64 + row) * 512 + Nbase + col + 4] = v1;
      }
    }
  }
}

__global__ __launch_bounds__(256) void gemm_out_kernel(
    const u16* __restrict__ Aat, const u16* __restrict__ Wob,
    float* __restrict__ Out, const float* __restrict__ bo) {
  gemm_core_bf16<2>(Aat, Wob, Out, bo, blockIdx.x * 128, blockIdx.y * 128);
}

// ---------------- flash attention v7 + setprio (best measured: 82.0 us, R1/R2) ------------
__global__ __launch_bounds__(256, 2) void attn_kernel(
    const u16* __restrict__ Q, const u16* __restrict__ K, const u16* __restrict__ Vt,
    u16* __restrict__ Oattn) {
  __shared__ __align__(16) u16 Ks[2][2][4096];
  __shared__ __align__(16) u16 Vs[2][2][4096];

  const int t = threadIdx.x;
  const int wave = t >> 6, lane = t & 63;
  const int r = lane & 15, qd = lane >> 4;
  const int g = wave & 1, kv = wave >> 1;
  const int bh = blockIdx.y;
  const int b = bh >> 3, h = bh & 7;
  const long bbase = (long)b * 4096 * 512;
  const int q0 = blockIdx.x * 128;

  const int sw = r & 7;
  const int ck0 = (qd ^ sw) * 8;
  const int ck1 = ((qd + 4) ^ sw) * 8;
  int vo0[2], vo1[2];
#pragma unroll
  for (int c = 0; c < 2; c++) {
    vo0[c] = ((c * 4 + (qd >> 1)) ^ sw) * 8 + 4 * (qd & 1);
    vo1[c] = ((c * 4 + 2 + (qd >> 1)) ^ sw) * 8 + 4 * (qd & 1);
  }

  bf16x8_t ones8;
#pragma unroll
  for (int j = 0; j < 8; j++) ones8[j] = (__bf16)1.0f;

  bf16x8_t qf[4][2];
#pragma unroll
  for (int qa = 0; qa < 4; qa++) {
    const u16* qp = Q + bbase + (long)(q0 + g * 64 + qa * 16 + r) * 512 + h * 64 + qd * 8;
    qf[qa][0] = *(const bf16x8_t*)(qp);
    qf[qa][1] = *(const bf16x8_t*)(qp + 32);
  }

  f32x4_t accO[4][4];
  f32x4_t accL[4];
#pragma unroll
  for (int qa = 0; qa < 4; qa++) {
    f32x4_t z = {0.f, 0.f, 0.f, 0.f};
    accL[qa] = z;
#pragma unroll
    for (int nt = 0; nt < 4; nt++) accO[qa][nt] = z;
  }

  const int rr = lane >> 3;
  const int cc = (lane & 7) ^ rr;
  const u16* kgb = K + bbase + (long)(kv * 2048 + g * 32 + rr) * 512 + h * 64 + cc * 8;
  const u16* vgb = Vt + ((long)(b * 512 + h * 64 + g * 32 + rr)) * 4096 + kv * 2048 + cc * 8;

#pragma unroll
  for (int i = 0; i < 4; i++) gl_lds16(kgb + (long)i * 8 * 512, &Ks[kv][0][g * 2048] + i * 512);
#pragma unroll
  for (int i = 0; i < 4; i++) gl_lds16(vgb + i * 8 * 4096, &Vs[kv][0][g * 2048] + i * 512);

  for (int it = 0; it < 32; it++) {
    const int buf = it & 1;
    __syncthreads();

    if (it < 31) {
      const int nb = (it + 1) & 1;
      const long ko = (long)(it + 1) * 64;
#pragma unroll
      for (int i = 0; i < 4; i++)
        gl_lds16(kgb + (ko + i * 8) * 512, &Ks[kv][nb][g * 2048] + i * 512);
#pragma unroll
      for (int i = 0; i < 4; i++)
        gl_lds16(vgb + ko + (long)i * 8 * 4096, &Vs[kv][nb][g * 2048] + i * 512);
    }

    bf16x8_t kf[4][2];
#pragma unroll
    for (int nt = 0; nt < 4; nt++) {
      const u16* kb = &Ks[kv][buf][(nt * 16 + r) * 64];
      kf[nt][0] = *(const bf16x8_t*)(kb + ck0);
      kf[nt][1] = *(const bf16x8_t*)(kb + ck1);
    }

    f32x4_t St[4][4];
    __builtin_amdgcn_s_setprio(1);
#pragma unroll
    for (int qa = 0; qa < 4; qa++)
#pragma unroll
      for (int nt = 0; nt < 4; nt++) {
        f32x4_t z = {0.f, 0.f, 0.f, 0.f};
        z = mfma16(kf[nt][0], qf[qa][0], z);
        z = mfma16(kf[nt][1], qf[qa][1], z);
        St[qa][nt] = z;
      }
    __builtin_amdgcn_s_setprio(0);

    bf16x8_t pf[4][2];
#pragma unroll
    for (int qa = 0; qa < 4; qa++)
#pragma unroll
      for (int c = 0; c < 2; c++) {
        f32x4_t e0, e1;
#pragma unroll
        for (int j = 0; j < 4; j++) {
          e0[j] = __builtin_amdgcn_exp2f(St[qa][2 * c][j]);
          e1[j] = __builtin_amdgcn_exp2f(St[qa][2 * c + 1][j]);
        }
        bf16x4_t b0 = __builtin_convertvector(e0, bf16x4_t);
        bf16x4_t b1 = __builtin_convertvector(e1, bf16x4_t);
        bf16x8_t p8;
#pragma unroll
        for (int j = 0; j < 4; j++) { p8[j] = b0[j]; p8[4 + j] = b1[j]; }
        pf[qa][c] = p8;
      }

#pragma unroll
    for (int qa = 0; qa < 4; qa++)
#pragma unroll
      for (int c = 0; c < 2; c++)
        accL[qa] = mfma16(ones8, pf[qa][c], accL[qa]);

#pragma unroll
    for (int c = 0; c < 2; c++) {
      bf16x8_t va[4];
#pragma unroll
      for (int dm = 0; dm < 4; dm++) {
        const u16* vb = &Vs[kv][buf][(dm * 16 + r) * 64];
        union { uint4 u; bf16x8_t v; } cat;
        *(uint2*)&cat.u.x = *(const uint2*)(vb + vo0[c]);
        *(uint2*)&cat.u.z = *(const uint2*)(vb + vo1[c]);
        va[dm] = cat.v;
      }
      __builtin_amdgcn_s_setprio(1);
#pragma unroll
      for (int qa = 0; qa < 4; qa++)
#pragma unroll
        for (int dm = 0; dm < 4; dm++)
          accO[qa][dm] = mfma16(va[dm], pf[qa][c], accO[qa][dm]);
      __builtin_amdgcn_s_setprio(0);
    }
  }

  __syncthreads();
  float* Sc  = (float*)&Ks[0][0][0];
  float* Lsc = (float*)&Vs[0][0][0];
  if (kv == 1) {
#pragma unroll
    for (int qa = 0; qa < 4; qa++) {
#pragma unroll
      for (int dm = 0; dm < 4; dm++)
        *(f32x4_t*)&Sc[g * 4096 + ((qa * 4 + dm) * 64 + lane) * 4] = accO[qa][dm];
      Lsc[g * 256 + qa * 64 + lane] = accL[qa][0];
    }
  }
  __syncthreads();
  if (kv == 0) {
#pragma unroll
    for (int qa = 0; qa < 4; qa++) {
      float L = accL[qa][0] + Lsc[g * 256 + qa * 64 + lane];
      float inv = 1.f / L;
      int gq = q0 + g * 64 + qa * 16 + r;
#pragma unroll
      for (int dm = 0; dm < 4; dm++) {
        f32x4_t o = *(const f32x4_t*)&Sc[g * 4096 + ((qa * 4 + dm) * 64 + lane) * 4];
        o += accO[qa][dm];
        bf16x4_t ob;
#pragma unroll
        for (int reg = 0; reg < 4; reg++) ob[reg] = (__bf16)(o[reg] * inv);
        *(uint2*)&Oattn[bbase + (long)gq * 512 + h * 64 + dm * 16 + qd * 4] = *(uint2*)&ob;
      }
    }
  }
}

// ---------------- launch ----------------
extern "C" void kernel_launch(void* const* d_in, const int* in_sizes, int n_in,
                              void* d_out, int out_size, void* d_ws, size_t ws_size,
                              hipStream_t stream) {
  const float* x  = (const float*)d_in[0];
  const float* Wq = (const float*)d_in[1];
  const float* Wk = (const float*)d_in[2];
  const float* Wv = (const float*)d_in[3];
  const float* Wo = (const float*)d_in[4];
  const float* bo = (const float*)d_in[5];
  float* out = (float*)d_out;

  u16* ws  = (u16*)d_ws;
  u16* Qb  = ws;
  u16* Kb  = Qb  + 4194304;
  u16* Vtg = Kb  + 4194304;   // V^T: [2*512][4096]
  u16* Ab  = Vtg + 4194304;
  u16* Xb  = Ab;              // aliased: Xb live [cast, qkv); Ab live [attn, out) — disjoint
  u16* Wqb = Ab  + 4194304;
  u16* Wkb = Wqb + 262144;
  u16* Wvb = Wkb + 262144;
  u16* Wob = Wvb + 262144;

  cast_kernel<<<2560, 256, 0, stream>>>(x, Wq, Wk, Wv, Wo, Xb, Wqb, Wkb, Wvb, Wob);

  dim3 g1(64, 4);
  gemm_qkv_fused<<<g1, 512, 0, stream>>>(Xb, Wqb, Wkb, Wvb, Qb, Kb, Vtg);

  dim3 g2(32, 16);
  attn_kernel<<<g2, 256, 0, stream>>>(Qb, Kb, Vtg, Ab);

  dim3 g3(64, 4);
  gemm_out_kernel<<<g3, 256, 0, stream>>>(Ab, Wob, out, bo);
}

// Round 9
// 176.850 us; speedup vs baseline: 1.7445x; 1.0190x over previous
//
#include <hip/hip_runtime.h>

// Problem constants: B=2, S=4096, H=8, DH=64, D=512, M = B*S = 8192.
#define LOG2E 1.44269504088896340736f

typedef unsigned short u16;
typedef __bf16 bf16x4_t __attribute__((ext_vector_type(4)));
typedef __bf16 bf16x8_t __attribute__((ext_vector_type(8)));
typedef float f32x4_t __attribute__((ext_vector_type(4)));

__device__ __forceinline__ f32x4_t mfma16(bf16x8_t a, bf16x8_t b, f32x4_t c) {
  return __builtin_amdgcn_mfma_f32_16x16x32_bf16(a, b, c, 0, 0, 0);
}

// async 16B global -> LDS (dest = wave-uniform base + lane*16)
__device__ __forceinline__ void gl_lds16(const u16* g, u16* l) {
  __builtin_amdgcn_global_load_lds(
      (const __attribute__((address_space(1))) unsigned int*)g,
      (__attribute__((address_space(3))) unsigned int*)l, 16, 0, 0);
}

// ---------------- one-shot cast: fp32 -> bf16 (Wq pre-scaled by 0.125*log2e) --------------
__global__ __launch_bounds__(256) void cast_kernel(
    const float* __restrict__ x, const float* __restrict__ Wq, const float* __restrict__ Wk,
    const float* __restrict__ Wv, const float* __restrict__ Wo,
    u16* __restrict__ Xb, u16* __restrict__ Wqb, u16* __restrict__ Wkb,
    u16* __restrict__ Wvb, u16* __restrict__ Wob) {
  const int bid = blockIdx.x;
  const float* src;
  u16* dst;
  float scale = 1.f;
  int rel;
  if (bid < 2048)      { src = x;  dst = Xb;  rel = bid; }
  else if (bid < 2176) { src = Wq; dst = Wqb; rel = bid - 2048; scale = 0.125f * LOG2E; }
  else if (bid < 2304) { src = Wk; dst = Wkb; rel = bid - 2176; }
  else if (bid < 2432) { src = Wv; dst = Wvb; rel = bid - 2304; }
  else                 { src = Wo; dst = Wob; rel = bid - 2432; }
  const int i = rel * 2048 + threadIdx.x * 8;
  f32x4_t a = *(const f32x4_t*)(src + i) * scale;
  f32x4_t b = *(const f32x4_t*)(src + i + 4) * scale;
  union { uint4 u; struct { bf16x4_t lo, hi; } s; } c;
  c.s.lo = __builtin_convertvector(a, bf16x4_t);
  c.s.hi = __builtin_convertvector(b, bf16x4_t);
  *(uint4*)(dst + i) = c.u;
}

// ---------------- fused QKV GEMM v2: 64x128 tile, 2 blocks/CU ------------------------------
// grid (128,4), 512 threads (8 waves, wn = wave owns 16 cols). LDS 56KB:
// As[64][64] + Bq/Bk/Bv[128][64]. Per K-step: 7 gl_lds/thread, 24 MFMA/wave.
// 2 blocks/CU -> cross-block overlap hides the stage-latency drain at each barrier.
__global__ __launch_bounds__(512) void gemm_qkv_fused(
    const u16* __restrict__ Xb,
    const u16* __restrict__ Wqb, const u16* __restrict__ Wkb, const u16* __restrict__ Wvb,
    u16* __restrict__ Q, u16* __restrict__ K, u16* __restrict__ Vt) {
  __shared__ __align__(16) u16 SM[28672];  // 56KB
  u16 (*As)[64] = (u16(*)[64])SM;                  // [64][64]
  u16 (*Bq)[64] = (u16(*)[64])(SM + 4096);         // [128][64]
  u16 (*Bk)[64] = (u16(*)[64])(SM + 12288);
  u16 (*Bv)[64] = (u16(*)[64])(SM + 20480);
  const int t = threadIdx.x;
  const int wave = t >> 6, lane = t & 63;
  const int r = lane & 15, qd = lane >> 4;
  const int wn = wave;  // 8 waves x 16 cols = 128
  const int rr = lane >> 3;
  const int s8 = ((lane & 7) ^ (rr & 7)) * 8;  // pre-swizzled global 16B slot
  const int Mbase = blockIdx.x * 64, Nbase = blockIdx.y * 128;

  f32x4_t acc[3][4];
#pragma unroll
  for (int w = 0; w < 3; w++)
#pragma unroll
    for (int i = 0; i < 4; i++) { f32x4_t z = {0.f, 0.f, 0.f, 0.f}; acc[w][i] = z; }

  const u16* pa = Xb  + (Mbase + wave * 8 + rr) * 512 + s8;
  const u16* pq = Wqb + (Nbase + wave * 16 + rr) * 512 + s8;
  const u16* pk = Wkb + (Nbase + wave * 16 + rr) * 512 + s8;
  const u16* pv = Wvb + (Nbase + wave * 16 + rr) * 512 + s8;
  u16* la = &As[wave * 8][0];
  u16* lq = &Bq[wave * 16][0];
  u16* lk = &Bk[wave * 16][0];
  u16* lv = &Bv[wave * 16][0];

  for (int k0 = 0; k0 < 512; k0 += 64) {
    gl_lds16(pa + k0, la);
#pragma unroll
    for (int p = 0; p < 2; p++) {
      gl_lds16(pq + k0 + p * 8 * 512, lq + p * 512);
      gl_lds16(pk + k0 + p * 8 * 512, lk + p * 512);
      gl_lds16(pv + k0 + p * 8 * 512, lv + p * 512);
    }
    __syncthreads();
#pragma unroll
    for (int h = 0; h < 2; h++) {
      const int cs = ((h * 4 + qd) ^ (r & 7)) * 8;
      bf16x8_t af[4];
#pragma unroll
      for (int i = 0; i < 4; i++) af[i] = *(const bf16x8_t*)&As[i * 16 + r][cs];
      bf16x8_t fq = *(const bf16x8_t*)&Bq[wn * 16 + r][cs];
      bf16x8_t fk = *(const bf16x8_t*)&Bk[wn * 16 + r][cs];
      bf16x8_t fv = *(const bf16x8_t*)&Bv[wn * 16 + r][cs];
#pragma unroll
      for (int i = 0; i < 4; i++) {
        acc[0][i] = mfma16(af[i], fq, acc[0][i]);
        acc[1][i] = mfma16(af[i], fk, acc[1][i]);
        acc[2][i] = mfma16(af[i], fv, acc[2][i]);
      }
    }
    __syncthreads();
  }

  // ---------------- epilogue: LDS-transpose, coalesced stores ----------------
  // Q then K: row-major [M][512]; C-tile 64x128 bf16 staged with slot-XOR swizzle.
#pragma unroll
  for (int w = 0; w < 2; w++) {
    __syncthreads();
    u16* dst = (w == 0) ? Q : K;
#pragma unroll
    for (int i = 0; i < 4; i++)
#pragma unroll
      for (int reg = 0; reg < 4; reg++) {
        int row = i * 16 + qd * 4 + reg;       // 0..63
        int col = wn * 16 + r;                 // 0..127
        __bf16 bvv = (__bf16)acc[w][i][reg];
        SM[row * 128 + (col ^ (((row >> 2) & 7) << 3))] = *(u16*)&bvv;
      }
    __syncthreads();
#pragma unroll
    for (int p = 0; p < 2; p++) {
      int row = p * 32 + (t >> 4);
      int col = (t & 15) * 8;
      uint4 v = *(const uint4*)&SM[row * 128 + (col ^ (((row >> 2) & 7) << 3))];
      *(uint4*)&dst[(Mbase + row) * 512 + Nbase + col] = v;
    }
  }
  // V: stage transposed [d][s] (128x64) so the V^T store is coalesced along s
  __syncthreads();
#pragma unroll
  for (int i = 0; i < 4; i++)
#pragma unroll
    for (int reg = 0; reg < 4; reg++) {
      int srow = i * 16 + qd * 4 + reg;        // s within tile, 0..63
      int dcol = wn * 16 + r;                  // d within tile, 0..127
      __bf16 bvv = (__bf16)acc[2][i][reg];
      SM[dcol * 64 + (srow ^ (((dcol >> 2) & 7) << 3))] = *(u16*)&bvv;
    }
  __syncthreads();
  {
    const int bb = Mbase >> 12;
    const int smod = Mbase & 4095;
#pragma unroll
    for (int p = 0; p < 2; p++) {
      int d = p * 64 + (t >> 3);
      int scol = (t & 7) * 8;
      uint4 v = *(const uint4*)&SM[d * 64 + (scol ^ (((d >> 2) & 7) << 3))];
      *(uint4*)&Vt[((long)(bb * 512 + Nbase + d)) * 4096 + smod + scol] = v;
    }
  }
}

// ---------------- out-proj GEMM v2: 64x128 tile, grid (128,4), 2+ blocks/CU ---------------
__global__ __launch_bounds__(512) void gemm_out_kernel(
    const u16* __restrict__ Aat, const u16* __restrict__ Wob,
    float* __restrict__ Out, const float* __restrict__ bo) {
  __shared__ __align__(16) u16 SM[16384];  // 32KB (K-loop uses 24KB; f32 epilogue uses 32KB)
  u16 (*As)[64] = (u16(*)[64])SM;                  // [64][64]
  u16 (*Bs)[64] = (u16(*)[64])(SM + 4096);         // [128][64]
  const int t = threadIdx.x;
  const int wave = t >> 6, lane = t & 63;
  const int r = lane & 15, qd = lane >> 4;
  const int wn = wave;
  const int rr = lane >> 3;
  const int s8 = ((lane & 7) ^ (rr & 7)) * 8;
  const int Mbase = blockIdx.x * 64, Nbase = blockIdx.y * 128;

  f32x4_t acc[4];
#pragma unroll
  for (int i = 0; i < 4; i++) { f32x4_t z = {0.f, 0.f, 0.f, 0.f}; acc[i] = z; }

  const u16* pa = Aat + (Mbase + wave * 8 + rr) * 512 + s8;
  const u16* pb = Wob + (Nbase + wave * 16 + rr) * 512 + s8;
  u16* la = &As[wave * 8][0];
  u16* lb = &Bs[wave * 16][0];

  for (int k0 = 0; k0 < 512; k0 += 64) {
    gl_lds16(pa + k0, la);
#pragma unroll
    for (int p = 0; p < 2; p++) gl_lds16(pb + k0 + p * 8 * 512, lb + p * 512);
    __syncthreads();
#pragma unroll
    for (int h = 0; h < 2; h++) {
      const int cs = ((h * 4 + qd) ^ (r & 7)) * 8;
      bf16x8_t af[4];
#pragma unroll
      for (int i = 0; i < 4; i++) af[i] = *(const bf16x8_t*)&As[i * 16 + r][cs];
      bf16x8_t bfr = *(const bf16x8_t*)&Bs[wn * 16 + r][cs];
#pragma unroll
      for (int i = 0; i < 4; i++) acc[i] = mfma16(af[i], bfr, acc[i]);
    }
    __syncthreads();
  }

  float* stf = (float*)SM;  // 64x128 f32 = 32KB
  float bv = bo[Nbase + wn * 16 + r];
#pragma unroll
  for (int i = 0; i < 4; i++)
#pragma unroll
    for (int reg = 0; reg < 4; reg++) {
      int row = i * 16 + qd * 4 + reg;   // 0..63
      int col = wn * 16 + r;             // 0..127
      stf[row * 128 + (col ^ (((row >> 2) & 7) << 2))] = acc[i][reg] + bv;
    }
  __syncthreads();
#pragma unroll
  for (int p = 0; p < 4; p++) {
    int row = p * 16 + (t >> 5);
    int col4 = (t & 31) * 4;
    f32x4_t v = *(const f32x4_t*)&stf[row * 128 + (col4 ^ (((row >> 2) & 7) << 2))];
    *(f32x4_t*)&Out[(Mbase + row) * 512 + Nbase + col4] = v;
  }
}

// ---------------- flash attention v7 + setprio (best measured: 82.0 us) -------------------
__global__ __launch_bounds__(256, 2) void attn_kernel(
    const u16* __restrict__ Q, const u16* __restrict__ K, const u16* __restrict__ Vt,
    u16* __restrict__ Oattn) {
  __shared__ __align__(16) u16 Ks[2][2][4096];
  __shared__ __align__(16) u16 Vs[2][2][4096];

  const int t = threadIdx.x;
  const int wave = t >> 6, lane = t & 63;
  const int r = lane & 15, qd = lane >> 4;
  const int g = wave & 1, kv = wave >> 1;
  const int bh = blockIdx.y;
  const int b = bh >> 3, h = bh & 7;
  const long bbase = (long)b * 4096 * 512;
  const int q0 = blockIdx.x * 128;

  const int sw = r & 7;
  const int ck0 = (qd ^ sw) * 8;
  const int ck1 = ((qd + 4) ^ sw) * 8;
  int vo0[2], vo1[2];
#pragma unroll
  for (int c = 0; c < 2; c++) {
    vo0[c] = ((c * 4 + (qd >> 1)) ^ sw) * 8 + 4 * (qd & 1);
    vo1[c] = ((c * 4 + 2 + (qd >> 1)) ^ sw) * 8 + 4 * (qd & 1);
  }

  bf16x8_t ones8;
#pragma unroll
  for (int j = 0; j < 8; j++) ones8[j] = (__bf16)1.0f;

  bf16x8_t qf[4][2];
#pragma unroll
  for (int qa = 0; qa < 4; qa++) {
    const u16* qp = Q + bbase + (long)(q0 + g * 64 + qa * 16 + r) * 512 + h * 64 + qd * 8;
    qf[qa][0] = *(const bf16x8_t*)(qp);
    qf[qa][1] = *(const bf16x8_t*)(qp + 32);
  }

  f32x4_t accO[4][4];
  f32x4_t accL[4];
#pragma unroll
  for (int qa = 0; qa < 4; qa++) {
    f32x4_t z = {0.f, 0.f, 0.f, 0.f};
    accL[qa] = z;
#pragma unroll
    for (int nt = 0; nt < 4; nt++) accO[qa][nt] = z;
  }

  const int rr = lane >> 3;
  const int cc = (lane & 7) ^ rr;
  const u16* kgb = K + bbase + (long)(kv * 2048 + g * 32 + rr) * 512 + h * 64 + cc * 8;
  const u16* vgb = Vt + ((long)(b * 512 + h * 64 + g * 32 + rr)) * 4096 + kv * 2048 + cc * 8;

#pragma unroll
  for (int i = 0; i < 4; i++) gl_lds16(kgb + (long)i * 8 * 512, &Ks[kv][0][g * 2048] + i * 512);
#pragma unroll
  for (int i = 0; i < 4; i++) gl_lds16(vgb + i * 8 * 4096, &Vs[kv][0][g * 2048] + i * 512);

  for (int it = 0; it < 32; it++) {
    const int buf = it & 1;
    __syncthreads();

    if (it < 31) {
      const int nb = (it + 1) & 1;
      const long ko = (long)(it + 1) * 64;
#pragma unroll
      for (int i = 0; i < 4; i++)
        gl_lds16(kgb + (ko + i * 8) * 512, &Ks[kv][nb][g * 2048] + i * 512);
#pragma unroll
      for (int i = 0; i < 4; i++)
        gl_lds16(vgb + ko + (long)i * 8 * 4096, &Vs[kv][nb][g * 2048] + i * 512);
    }

    bf16x8_t kf[4][2];
#pragma unroll
    for (int nt = 0; nt < 4; nt++) {
      const u16* kb = &Ks[kv][buf][(nt * 16 + r) * 64];
      kf[nt][0] = *(const bf16x8_t*)(kb + ck0);
      kf[nt][1] = *(const bf16x8_t*)(kb + ck1);
    }

    f32x4_t St[4][4];
    __builtin_amdgcn_s_setprio(1);
#pragma unroll
    for (int qa = 0; qa < 4; qa++)
#pragma unroll
      for (int nt = 0; nt < 4; nt++) {
        f32x4_t z = {0.f, 0.f, 0.f, 0.f};
        z = mfma16(kf[nt][0], qf[qa][0], z);
        z = mfma16(kf[nt][1], qf[qa][1], z);
        St[qa][nt] = z;
      }
    __builtin_amdgcn_s_setprio(0);

    bf16x8_t pf[4][2];
#pragma unroll
    for (int qa = 0; qa < 4; qa++)
#pragma unroll
      for (int c = 0; c < 2; c++) {
        f32x4_t e0, e1;
#pragma unroll
        for (int j = 0; j < 4; j++) {
          e0[j] = __builtin_amdgcn_exp2f(St[qa][2 * c][j]);
          e1[j] = __builtin_amdgcn_exp2f(St[qa][2 * c + 1][j]);
        }
        bf16x4_t b0 = __builtin_convertvector(e0, bf16x4_t);
        bf16x4_t b1 = __builtin_convertvector(e1, bf16x4_t);
        bf16x8_t p8;
#pragma unroll
        for (int j = 0; j < 4; j++) { p8[j] = b0[j]; p8[4 + j] = b1[j]; }
        pf[qa][c] = p8;
      }

#pragma unroll
    for (int qa = 0; qa < 4; qa++)
#pragma unroll
      for (int c = 0; c < 2; c++)
        accL[qa] = mfma16(ones8, pf[qa][c], accL[qa]);

#pragma unroll
    for (int c = 0; c < 2; c++) {
      bf16x8_t va[4];
#pragma unroll
      for (int dm = 0; dm < 4; dm++) {
        const u16* vb = &Vs[kv][buf][(dm * 16 + r) * 64];
        union { uint4 u; bf16x8_t v; } cat;
        *(uint2*)&cat.u.x = *(const uint2*)(vb + vo0[c]);
        *(uint2*)&cat.u.z = *(const uint2*)(vb + vo1[c]);
        va[dm] = cat.v;
      }
      __builtin_amdgcn_s_setprio(1);
#pragma unroll
      for (int qa = 0; qa < 4; qa++)
#pragma unroll
        for (int dm = 0; dm < 4; dm++)
          accO[qa][dm] = mfma16(va[dm], pf[qa][c], accO[qa][dm]);
      __builtin_amdgcn_s_setprio(0);
    }
  }

  __syncthreads();
  float* Sc  = (float*)&Ks[0][0][0];
  float* Lsc = (float*)&Vs[0][0][0];
  if (kv == 1) {
#pragma unroll
    for (int qa = 0; qa < 4; qa++) {
#pragma unroll
      for (int dm = 0; dm < 4; dm++)
        *(f32x4_t*)&Sc[g * 4096 + ((qa * 4 + dm) * 64 + lane) * 4] = accO[qa][dm];
      Lsc[g * 256 + qa * 64 + lane] = accL[qa][0];
    }
  }
  __syncthreads();
  if (kv == 0) {
#pragma unroll
    for (int qa = 0; qa < 4; qa++) {
      float L = accL[qa][0] + Lsc[g * 256 + qa * 64 + lane];
      float inv = 1.f / L;
      int gq = q0 + g * 64 + qa * 16 + r;
#pragma unroll
      for (int dm = 0; dm < 4; dm++) {
        f32x4_t o = *(const f32x4_t*)&Sc[g * 4096 + ((qa * 4 + dm) * 64 + lane) * 4];
        o += accO[qa][dm];
        bf16x4_t ob;
#pragma unroll
        for (int reg = 0; reg < 4; reg++) ob[reg] = (__bf16)(o[reg] * inv);
        *(uint2*)&Oattn[bbase + (long)gq * 512 + h * 64 + dm * 16 + qd * 4] = *(uint2*)&ob;
      }
    }
  }
}

// ---------------- launch ----------------
extern "C" void kernel_launch(void* const* d_in, const int* in_sizes, int n_in,
                              void* d_out, int out_size, void* d_ws, size_t ws_size,
                              hipStream_t stream) {
  const float* x  = (const float*)d_in[0];
  const float* Wq = (const float*)d_in[1];
  const float* Wk = (const float*)d_in[2];
  const float* Wv = (const float*)d_in[3];
  const float* Wo = (const float*)d_in[4];
  const float* bo = (const float*)d_in[5];
  float* out = (float*)d_out;

  u16* ws  = (u16*)d_ws;
  u16* Qb  = ws;
  u16* Kb  = Qb  + 4194304;
  u16* Vtg = Kb  + 4194304;   // V^T: [2*512][4096]
  u16* Ab  = Vtg + 4194304;
  u16* Xb  = Ab;              // aliased: Xb live [cast, qkv); Ab live [attn, out) — disjoint
  u16* Wqb = Ab  + 4194304;
  u16* Wkb = Wqb + 262144;
  u16* Wvb = Wkb + 262144;
  u16* Wob = Wvb + 262144;

  cast_kernel<<<2560, 256, 0, stream>>>(x, Wq, Wk, Wv, Wo, Xb, Wqb, Wkb, Wvb, Wob);

  dim3 g1(128, 4);
  gemm_qkv_fused<<<g1, 512, 0, stream>>>(Xb, Wqb, Wkb, Wvb, Qb, Kb, Vtg);

  dim3 g2(32, 16);
  attn_kernel<<<g2, 256, 0, stream>>>(Qb, Kb, Vtg, Ab);

  dim3 g3(128, 4);
  gemm_out_kernel<<<g3, 512, 0, stream>>>(Ab, Wob, out, bo);
}